// Round 8
// baseline (3315.146 us; speedup 1.0000x reference)
//
#include <hip/hip_runtime.h>
#include <stdint.h>
#include <math.h>

typedef _Float16 half_t;
typedef _Float16 f16x8 __attribute__((ext_vector_type(8)));
typedef float f32x4 __attribute__((ext_vector_type(4)));
typedef float f32x16 __attribute__((ext_vector_type(16)));

#define SLOPE 0.01f

__device__ inline float leaky(float v) { return v > 0.f ? v : SLOPE * v; }

__device__ inline void stage16(const half_t* g, half_t* l) {
    __builtin_amdgcn_global_load_lds(
        (const __attribute__((address_space(1))) unsigned int*)g,
        (__attribute__((address_space(3))) unsigned int*)l, 16, 0, 0);
}

__device__ inline float softplusf(float v) {
    return v > 20.f ? v : log1pf(expf(v));
}

// ---------------------------------------------------------------------------
// Weight prep: cast/reorder conv weights to oc-major fp16 (v4 layout).
// ---------------------------------------------------------------------------
__global__ void prep_kernel(const float* __restrict__ W1, const float* __restrict__ W2,
                            const float* __restrict__ W3,
                            half_t* __restrict__ B1w, half_t* __restrict__ B2w,
                            half_t* __restrict__ B3w)
{
    const unsigned idx = blockIdx.x * 256u + threadIdx.x;
    const unsigned n2 = 768u * 6912u;                 // 5,308,416
    if (idx < n2) {
        unsigned oc = idx / 6912u;
        unsigned rem = idx - oc * 6912u;
        unsigned tap = rem / 768u;
        unsigned ic = rem - tap * 768u;
        unsigned ky = tap / 3u, kx = tap - ky * 3u;
        B2w[idx] = (half_t)W2[(((size_t)oc * 768u + ic) * 3u + ky) * 3u + kx];
    } else if (idx < n2 + 147456u) {
        unsigned i = idx - n2;
        B1w[i] = (half_t)W1[i];                       // W1 flat is already (oc,ic)
    } else if (idx < n2 + 294912u) {
        unsigned i = idx - n2 - 147456u;
        B3w[i] = (half_t)W3[i];                       // W3 flat is already (oc,ic)
    }
}

// ---------------------------------------------------------------------------
// Per-window linear attention. One block per window. Writes feat NHWC fp16.
// ---------------------------------------------------------------------------
__global__ __launch_bounds__(256, 2)
void attn_kernel(const float* __restrict__ x,
                 const float* __restrict__ Wq, const float* __restrict__ bq,
                 const float* __restrict__ Wk, const float* __restrict__ bk,
                 const float* __restrict__ Wv, const float* __restrict__ bv,
                 const float* __restrict__ Wo, const float* __restrict__ bo,
                 half_t* __restrict__ featN)
{
    __shared__ half_t xls[192 * 65];
    __shared__ float wqL[512], wkL[512], wvL[512], woL[512];
    __shared__ float bqL[8], bkL[8], bvL[8], boL[64];
    __shared__ float kls[192 * 9], vls[192 * 9];
    __shared__ float sls[64];

    const int t = threadIdx.x;
    const int blk = blockIdx.x;
    const int b = blk >> 10;
    const int n = blk & 1023;
    const int wi = n >> 5, wj = n & 31;

    for (int i = t; i < 512; i += 256) {
        wqL[i] = Wq[i]; wkL[i] = Wk[i]; wvL[i] = Wv[i]; woL[i] = Wo[i];
    }
    if (t < 8)  { bqL[t] = bq[t]; bkL[t] = bk[t]; bvL[t] = bv[t]; }
    if (t < 64) boL[t] = bo[t];

    #pragma unroll
    for (int i = 0; i < 6; ++i) {
        int idx = t + i * 256;                 // 0..1535 = (c,py)
        int c = idx >> 3, py = idx & 7;
        const float* src = x + (((size_t)b * 192 + c) * 256 + (wi * 8 + py)) * 256 + wj * 8;
        float4 v0 = *(const float4*)src;
        float4 v1 = *(const float4*)(src + 4);
        half_t* dst = &xls[c * 65 + py * 8];
        dst[0] = (half_t)v0.x; dst[1] = (half_t)v0.y; dst[2] = (half_t)v0.z; dst[3] = (half_t)v0.w;
        dst[4] = (half_t)v1.x; dst[5] = (half_t)v1.y; dst[6] = (half_t)v1.z; dst[7] = (half_t)v1.w;
    }
    __syncthreads();

    float qf[8], kf[8], vf[8];
    if (t < 192) {
        #pragma unroll
        for (int d = 0; d < 8; ++d) { qf[d] = bqL[d]; kf[d] = bkL[d]; vf[d] = bvL[d]; }
        const half_t* xr = &xls[t * 65];
        for (int p = 0; p < 64; ++p) {
            float xv = (float)xr[p];
            const float* wqp = &wqL[p * 8];
            const float* wkp = &wkL[p * 8];
            const float* wvp = &wvL[p * 8];
            #pragma unroll
            for (int d = 0; d < 8; ++d) {
                qf[d] += xv * wqp[d];
                kf[d] += xv * wkp[d];
                vf[d] += xv * wvp[d];
            }
        }
        #pragma unroll
        for (int d = 0; d < 8; ++d) {
            qf[d] = softplusf(qf[d]);
            kf[d] = softplusf(kf[d]);
            kls[t * 9 + d] = kf[d];
            vls[t * 9 + d] = vf[d];
        }
    }
    __syncthreads();
    if (t < 64) {
        int e = t >> 3, dd = t & 7;
        float s = 0.f;
        for (int c = 0; c < 192; ++c) s += kls[c * 9 + e] * vls[c * 9 + dd];
        sls[t] = s;
    }
    __syncthreads();
    if (t < 192) {
        float rf[8];
        #pragma unroll
        for (int d = 0; d < 8; ++d) {
            float s = 0.f;
            #pragma unroll
            for (int e = 0; e < 8; ++e) s += qf[e] * sls[e * 8 + d];
            rf[d] = s;
        }
        half_t* xr = &xls[t * 65];
        for (int p = 0; p < 64; ++p) {
            float a = boL[p];
            #pragma unroll
            for (int d = 0; d < 8; ++d) a += rf[d] * woL[d * 64 + p];
            xr[p] = (half_t)((float)xr[p] + a);
        }
    }
    __syncthreads();
    half_t* dst = featN + ((size_t)b * 65536 + (size_t)n * 64) * 192;
    for (int i = 0; i < 48; ++i) {
        int idx = t + i * 256;                 // 0..12287 = p*192 + c
        int p = idx / 192, c = idx - p * 192;
        dst[idx] = xls[c * 65 + p];
    }
}

// ---------------------------------------------------------------------------
// conv1: 1x1 192->768 + leaky. GEMM M=65536 (one batch), N=768, K=192.
// ---------------------------------------------------------------------------
__global__ __launch_bounds__(256, 2)
void conv1_kernel(const half_t* __restrict__ featN, const half_t* __restrict__ B1w,
                  const float* __restrict__ b1, half_t* __restrict__ h1p, int batch)
{
    __shared__ half_t As[128 * 64];
    __shared__ half_t Bs[128 * 64];
    const int t = threadIdx.x;
    const int lane = t & 63;
    const int w = t >> 6;
    const int m0 = blockIdx.x * 128;
    const int n0 = blockIdx.y * 128;
    const int wm = (w >> 1) * 64, wn = (w & 1) * 64;
    const int rbase = t >> 3;
    const int g = (t & 7) ^ (rbase & 7);
    const int ar = lane & 15, kc = lane >> 4;

    f32x4 acc[4][4];
    #pragma unroll
    for (int i = 0; i < 4; ++i)
        #pragma unroll
        for (int j = 0; j < 4; ++j) acc[i][j] = (f32x4){0.f, 0.f, 0.f, 0.f};

    const size_t mb = (size_t)batch * 65536 + m0;

    for (int s = 0; s < 3; ++s) {
        const int k0 = s * 64;
        const half_t* ga = featN + (mb + rbase) * 192 + k0 + g * 8;
        const half_t* gb = B1w + (size_t)(n0 + rbase) * 192 + k0 + g * 8;
        half_t* la = As + t * 8;
        half_t* lb = Bs + t * 8;
        #pragma unroll
        for (int i = 0; i < 4; ++i) {
            stage16(ga + (size_t)32 * i * 192, la + 2048 * i);
            stage16(gb + (size_t)32 * i * 192, lb + 2048 * i);
        }
        __syncthreads();
        #pragma unroll
        for (int kh = 0; kh < 2; ++kh) {
            f16x8 af[4], bfr[4];
            const int c = kh * 4 + kc;
            #pragma unroll
            for (int mf = 0; mf < 4; ++mf) {
                int r = wm + mf * 16 + ar;
                af[mf] = *(const f16x8*)&As[(r * 8 + (c ^ (r & 7))) * 8];
            }
            #pragma unroll
            for (int nf = 0; nf < 4; ++nf) {
                int r = wn + nf * 16 + ar;
                bfr[nf] = *(const f16x8*)&Bs[(r * 8 + (c ^ (r & 7))) * 8];
            }
            #pragma unroll
            for (int mf = 0; mf < 4; ++mf)
                #pragma unroll
                for (int nf = 0; nf < 4; ++nf)
                    acc[mf][nf] = __builtin_amdgcn_mfma_f32_16x16x32_f16(af[mf], bfr[nf], acc[mf][nf], 0, 0, 0);
        }
        __syncthreads();
    }

    const int y = m0 >> 8, x0 = m0 & 255;
    half_t* outrow = h1p + ((size_t)(y + 1) * 258 + (x0 + 1)) * 768;
    #pragma unroll
    for (int nf = 0; nf < 4; ++nf) {
        int n = n0 + wn + nf * 16 + ar;
        float bias = b1[n];
        #pragma unroll
        for (int mf = 0; mf < 4; ++mf) {
            #pragma unroll
            for (int r4 = 0; r4 < 4; ++r4) {
                int local = wm + mf * 16 + kc * 4 + r4;
                outrow[(size_t)local * 768 + n] = (half_t)leaky(acc[mf][nf][r4] + bias);
            }
        }
    }
}

// ---------------------------------------------------------------------------
// conv2 v8 = EXACT v4 skeleton (schedule/stages/waits/grid/swizzle) with the
// MFMA geometry swapped to 32x32x16: per phase 8 MFMA (2 mf x 4 k-slices)
// instead of 16, same 12 ds_read_b128/phase, same lgkm(12/8/0)/vmcnt(8).
// A/B lane layout: [l&31][(l>>5)*8+j]; C/D: col=lane&31,
// row=(reg&3)+8*(reg>>2)+4*(lane>>5) (m74/m101-verified mapping).
// ---------------------------------------------------------------------------
__device__ __forceinline__ void c2_stage_A(half_t* As, int buf, int h,
    const half_t* __restrict__ h1p, int y, int kstep, int t, int cg)
{
    const int tap = kstep / 12, icc = kstep - tap * 12;
    const int ky = tap / 3, kx = tap - ky * 3;
    const int row0 = t >> 3;
    const half_t* g = h1p + ((size_t)(y + ky) * 258 + (kx + h * 128 + row0)) * 768
                      + icc * 64 + cg;
    half_t* l = As + (buf * 2 + h) * 8192 + t * 8;
    stage16(g, l);
    stage16(g + (size_t)64 * 768, l + 4096);
}

__device__ __forceinline__ void c2_stage_B(half_t* Bs, int buf, int h,
    const half_t* __restrict__ B2w, int n0, int kstep, int t, int cg)
{
    const int tap = kstep / 12, icc = kstep - tap * 12;
    const int row0 = t >> 3;
    const half_t* g = B2w + (size_t)(n0 + h * 128 + row0) * 6912
                      + tap * 768 + icc * 64 + cg;
    half_t* l = Bs + (buf * 2 + h) * 8192 + t * 8;
    stage16(g, l);
    stage16(g + (size_t)64 * 6912, l + 4096);
}

#define SBAR __builtin_amdgcn_s_barrier()
#define SB0  __builtin_amdgcn_sched_barrier(0)
#define LGKM(N) asm volatile("s_waitcnt lgkmcnt(" #N ")" ::: "memory")
#define VMC(N)  asm volatile("s_waitcnt vmcnt(" #N ")" ::: "memory")

// 8 ds_read_b128 into af[MQ]: mf in 0..1 (32-row frags), ks in 0..3 (K=16 slices)
#define RDA(MQ, BUF)                                                             \
  _Pragma("unroll")                                                              \
  for (int mf = 0; mf < 2; ++mf)                                                 \
    _Pragma("unroll")                                                            \
    for (int ks = 0; ks < 4; ++ks) {                                             \
      const int lr = wm * 64 + mf * 32 + ar32;                                   \
      const int ch = (ks * 2 + hi) ^ (lr & 7);                                   \
      af[MQ][mf][ks] = *(const f16x8*)&As[((BUF)*2 + (MQ))*8192 + lr*64 + ch*8]; \
    }

// 4 ds_read_b128 into bf[NQ]: ks in 0..3
#define RDB(NQ, BUF)                                                             \
  _Pragma("unroll")                                                              \
  for (int ks = 0; ks < 4; ++ks) {                                               \
    const int lc = wn * 32 + ar32;                                               \
    const int ch = (ks * 2 + hi) ^ (lc & 7);                                     \
    bf[NQ][ks] = *(const f16x8*)&Bs[((BUF)*2 + (NQ))*8192 + lc*64 + ch*8];       \
  }

#define MMA8(MQ, NQ)                                                             \
  {                                                                              \
    __builtin_amdgcn_s_setprio(1);                                               \
    _Pragma("unroll")                                                            \
    for (int ks = 0; ks < 4; ++ks)                                               \
      _Pragma("unroll")                                                          \
      for (int mf = 0; mf < 2; ++mf)                                             \
        acc[(MQ)*2+(NQ)][mf] = __builtin_amdgcn_mfma_f32_32x32x16_f16(           \
            af[MQ][mf][ks], bf[NQ][ks], acc[(MQ)*2+(NQ)][mf], 0, 0, 0);          \
    __builtin_amdgcn_s_setprio(0);                                               \
  }

__global__ __launch_bounds__(512, 2)
void conv2_kernel(const half_t* __restrict__ h1p, const half_t* __restrict__ B2w,
                  const float* __restrict__ b2, half_t* __restrict__ h2)
{
    __shared__ half_t As[4 * 8192];    // [buf][half][128][64] f16 = 64 KiB
    __shared__ half_t Bs[4 * 8192];

    const int t = threadIdx.x;
    const int lane = t & 63;
    const int w = t >> 6;
    const int wm = w >> 2, wn = w & 3;            // 2x4 wave grid inside a quadrant
    const int ar32 = lane & 31, hi = lane >> 5;
    const int cg = (((t & 7) ^ ((t >> 3) & 7)) << 3);  // pre-swizzled source chunk

    // v4 grid: nt innermost + XCD-chunked mtile bands.
    const int bid = blockIdx.x;
    const int xcd = bid & 7, sid = bid >> 3;      // 96 blocks per XCD
    const int wg = xcd * 96 + sid;                // 768 = 8 XCD * 96
    const int mtile = wg / 3;
    const int nt = wg - mtile * 3;
    const int y = mtile;
    const int m0 = mtile * 256;
    const int n0 = nt * 256;

    f32x16 acc[4][2];                             // [quadrant][mf]
    #pragma unroll
    for (int q = 0; q < 4; ++q)
        #pragma unroll
        for (int mf = 0; mf < 2; ++mf)
            #pragma unroll
            for (int e = 0; e < 16; ++e) acc[q][mf][e] = 0.f;

    f16x8 af[2][2][4];   // [MQ][mf][ks]
    f16x8 bf[2][4];      // [NQ][ks]

    // Prologue: stage buf0<-k0, buf1<-k1 fully; drain; issue boundary reads.
    c2_stage_A(As, 0, 0, h1p, y, 0, t, cg);
    c2_stage_A(As, 0, 1, h1p, y, 0, t, cg);
    c2_stage_B(Bs, 0, 0, B2w, n0, 0, t, cg);
    c2_stage_B(Bs, 0, 1, B2w, n0, 0, t, cg);
    c2_stage_A(As, 1, 0, h1p, y, 1, t, cg);
    c2_stage_A(As, 1, 1, h1p, y, 1, t, cg);
    c2_stage_B(Bs, 1, 0, B2w, n0, 1, t, cg);
    c2_stage_B(Bs, 1, 1, B2w, n0, 1, t, cg);
    VMC(0);
    SBAR; SB0;
    RDB(0, 0); SB0;
    RDA(0, 0);

    // Steady: 53 iterations (compute kt 0..105; stage up to kt 107).
    for (int i = 0; i < 53; ++i) {
        const int k2 = 2 * i + 2;
        const int k3 = 2 * i + 3;
        // ph1 (q00 buf0): read-ahead bf1,af1 of buf0.
        RDB(1, 0); SB0;
        RDA(1, 0);
        LGKM(12); SB0;
        MMA8(0, 0);
        SBAR;
        // ph2 (q01 buf0): stage A0h0,B0h0 <- k2.
        c2_stage_A(As, 0, 0, h1p, y, k2, t, cg);
        c2_stage_B(Bs, 0, 0, B2w, n0, k2, t, cg);
        LGKM(8); SB0;
        MMA8(0, 1);
        SBAR;
        // ph3 (q11 buf0).
        LGKM(0); SB0;
        MMA8(1, 1);
        SBAR;
        // ph4 (q10 buf0): stage A0h1,B0h1 <- k2; vmcnt(8); post-reads buf1.
        c2_stage_A(As, 0, 1, h1p, y, k2, t, cg);
        c2_stage_B(Bs, 0, 1, B2w, n0, k2, t, cg);
        VMC(8);
        SBAR; SB0;
        MMA8(1, 0);
        SB0;
        RDB(0, 1); SB0;
        RDA(0, 1);
        SBAR;
        // ph5 (q00 buf1): read-ahead bf1,af1 of buf1.
        RDB(1, 1); SB0;
        RDA(1, 1);
        LGKM(12); SB0;
        MMA8(0, 0);
        SBAR;
        // ph6 (q01 buf1): stage A1h0,B1h0 <- k3.
        c2_stage_A(As, 1, 0, h1p, y, k3, t, cg);
        c2_stage_B(Bs, 1, 0, B2w, n0, k3, t, cg);
        LGKM(8); SB0;
        MMA8(0, 1);
        SBAR;
        // ph7 (q11 buf1).
        LGKM(0); SB0;
        MMA8(1, 1);
        SBAR;
        // ph8 (q10 buf1): stage A1h1,B1h1 <- k3; vmcnt(8); post-reads buf0 next.
        c2_stage_A(As, 1, 1, h1p, y, k3, t, cg);
        c2_stage_B(Bs, 1, 1, B2w, n0, k3, t, cg);
        VMC(8);
        SBAR; SB0;
        MMA8(1, 0);
        SB0;
        RDB(0, 0); SB0;
        RDA(0, 0);
        SBAR;
    }
    // Tail (kt 106,107): no stages, no next-buffer reads.
    {
        // ph1
        RDB(1, 0); SB0;
        RDA(1, 0);
        LGKM(12); SB0;
        MMA8(0, 0);
        SBAR;
        // ph2
        LGKM(8); SB0;
        MMA8(0, 1);
        SBAR;
        // ph3
        LGKM(0); SB0;
        MMA8(1, 1);
        SBAR;
        // ph4: drain all remaining stages, then buf1 reads.
        VMC(0);
        SBAR; SB0;
        MMA8(1, 0);
        SB0;
        RDB(0, 1); SB0;
        RDA(0, 1);
        SBAR;
        // ph5
        RDB(1, 1); SB0;
        RDA(1, 1);
        LGKM(12); SB0;
        MMA8(0, 0);
        SBAR;
        // ph6
        LGKM(8); SB0;
        MMA8(0, 1);
        SBAR;
        // ph7
        LGKM(0); SB0;
        MMA8(1, 1);
        SBAR;
        // ph8
        MMA8(1, 0);
    }

    // Epilogue: bias + leaky, write NHWC fp16.
    // C/D 32x32 mapping: col = frag_col + (lane&31),
    // row = frag_row + (reg&3) + 8*(reg>>2) + 4*(lane>>5).
    #pragma unroll
    for (int q = 0; q < 4; ++q) {
        const int mq = q >> 1, nq = q & 1;
        const int col = n0 + nq * 128 + wn * 32 + ar32;
        const float bias = b2[col];
        #pragma unroll
        for (int mf = 0; mf < 2; ++mf) {
            const int rowbase = m0 + mq * 128 + wm * 64 + mf * 32 + hi * 4;
            half_t* op = h2 + (size_t)rowbase * 768 + col;
            #pragma unroll
            for (int reg = 0; reg < 16; ++reg) {
                const int roff = (reg & 3) + 8 * (reg >> 2);
                op[(size_t)roff * 768] = (half_t)leaky(acc[q][mf][reg] + bias);
            }
        }
    }
}

// ---------------------------------------------------------------------------
// conv3: 1x1 768->192 + leaky. GEMM M=65536 (one batch), N=192, K=768.
// ---------------------------------------------------------------------------
__global__ __launch_bounds__(256, 2)
void conv3_kernel(const half_t* __restrict__ h2, const half_t* __restrict__ B3w,
                  const float* __restrict__ b3, float* __restrict__ out, int batch)
{
    __shared__ half_t As[128 * 64];
    __shared__ half_t Bs[192 * 64];
    const int t = threadIdx.x;
    const int lane = t & 63;
    const int w = t >> 6;
    const int m0 = blockIdx.x * 128;
    const int wm = (w >> 1) * 64;
    const int wn = (w & 1) * 96;
    const int rbase = t >> 3;
    const int g = (t & 7) ^ (rbase & 7);
    const int ar = lane & 15, kc = lane >> 4;

    f32x4 acc[4][6];
    #pragma unroll
    for (int i = 0; i < 4; ++i)
        #pragma unroll
        for (int j = 0; j < 6; ++j) acc[i][j] = (f32x4){0.f, 0.f, 0.f, 0.f};

    for (int s = 0; s < 12; ++s) {
        const int k0 = s * 64;
        const half_t* ga = h2 + (size_t)(m0 + rbase) * 768 + k0 + g * 8;
        const half_t* gb = B3w + (size_t)rbase * 768 + k0 + g * 8;
        half_t* la = As + t * 8;
        half_t* lb = Bs + t * 8;
        #pragma unroll
        for (int i = 0; i < 4; ++i) stage16(ga + (size_t)32 * i * 768, la + 2048 * i);
        #pragma unroll
        for (int i = 0; i < 6; ++i) stage16(gb + (size_t)32 * i * 768, lb + 2048 * i);
        __syncthreads();
        #pragma unroll
        for (int kh = 0; kh < 2; ++kh) {
            f16x8 af[4], bfr[6];
            const int c = kh * 4 + kc;
            #pragma unroll
            for (int mf = 0; mf < 4; ++mf) {
                int r = wm + mf * 16 + ar;
                af[mf] = *(const f16x8*)&As[(r * 8 + (c ^ (r & 7))) * 8];
            }
            #pragma unroll
            for (int nf = 0; nf < 6; ++nf) {
                int r = wn + nf * 16 + ar;
                bfr[nf] = *(const f16x8*)&Bs[(r * 8 + (c ^ (r & 7))) * 8];
            }
            #pragma unroll
            for (int mf = 0; mf < 4; ++mf)
                #pragma unroll
                for (int nf = 0; nf < 6; ++nf)
                    acc[mf][nf] = __builtin_amdgcn_mfma_f32_16x16x32_f16(af[mf], bfr[nf], acc[mf][nf], 0, 0, 0);
        }
        __syncthreads();
    }

    #pragma unroll
    for (int nf = 0; nf < 6; ++nf) {
        int n = wn + nf * 16 + ar;
        float bias = b3[n];
        float* op = out + ((size_t)batch * 192 + n) * 65536 + m0;
        #pragma unroll
        for (int mf = 0; mf < 4; ++mf) {
            int local = wm + mf * 16 + kc * 4;
            f32x4 v;
            #pragma unroll
            for (int r4 = 0; r4 < 4; ++r4) v[r4] = leaky(acc[mf][nf][r4] + bias);
            *(f32x4*)(op + local) = v;
        }
    }
}

// ---------------------------------------------------------------------------
extern "C" void kernel_launch(void* const* d_in, const int* in_sizes, int n_in,
                              void* d_out, int out_size, void* d_ws, size_t ws_size,
                              hipStream_t stream)
{
    const float* x  = (const float*)d_in[0];
    const float* Wq = (const float*)d_in[1];
    const float* bq = (const float*)d_in[2];
    const float* Wk = (const float*)d_in[3];
    const float* bk = (const float*)d_in[4];
    const float* Wv = (const float*)d_in[5];
    const float* bv = (const float*)d_in[6];
    const float* Wo = (const float*)d_in[7];
    const float* bo = (const float*)d_in[8];
    const float* W1 = (const float*)d_in[9];
    const float* b1 = (const float*)d_in[10];
    const float* W2 = (const float*)d_in[11];
    const float* b2 = (const float*)d_in[12];
    const float* W3 = (const float*)d_in[13];
    const float* b3 = (const float*)d_in[14];

    char* ws = (char*)d_ws;
    const size_t OFF_B1   = 0;
    const size_t OFF_B3   = 294912;
    const size_t OFF_B2   = 589824;
    const size_t OFF_FEAT = 11206656;
    const size_t OFF_H1P  = 111869952;
    const size_t OFF_H2   = 214124544;
    const size_t WS_NEED  = 314787840;
    if (ws_size < WS_NEED) return;

    half_t* B1w   = (half_t*)(ws + OFF_B1);
    half_t* B3w   = (half_t*)(ws + OFF_B3);
    half_t* B2w   = (half_t*)(ws + OFF_B2);
    half_t* featN = (half_t*)(ws + OFF_FEAT);
    half_t* h1p   = (half_t*)(ws + OFF_H1P);
    half_t* h2    = (half_t*)(ws + OFF_H2);

    hipMemsetAsync(h1p, 0, 102254592, stream);
    prep_kernel<<<21888, 256, 0, stream>>>(W1, W2, W3, B1w, B2w, B3w);
    attn_kernel<<<4096, 256, 0, stream>>>(x, Wq, bq, Wk, bk, Wv, bv, Wo, bo, featN);

    for (int b = 0; b < 4; ++b) {
        conv1_kernel<<<dim3(512, 6), 256, 0, stream>>>(featN, B1w, b1, h1p, b);
        conv2_kernel<<<768, 512, 0, stream>>>(h1p, B2w, b2, h2);
        conv3_kernel<<<dim3(512, 1), 256, 0, stream>>>(h2, B3w, b3, (float*)d_out, b);
    }
}

// Round 9
// 2875.618 us; speedup vs baseline: 1.1528x; 1.1528x over previous
//
#include <hip/hip_runtime.h>
#include <stdint.h>
#include <math.h>

typedef _Float16 half_t;
typedef _Float16 f16x8 __attribute__((ext_vector_type(8)));
typedef float f32x4 __attribute__((ext_vector_type(4)));

#define SLOPE 0.01f

__device__ inline float leaky(float v) { return v > 0.f ? v : SLOPE * v; }

__device__ inline void stage16(const half_t* g, half_t* l) {
    __builtin_amdgcn_global_load_lds(
        (const __attribute__((address_space(1))) unsigned int*)g,
        (__attribute__((address_space(3))) unsigned int*)l, 16, 0, 0);
}

__device__ inline float softplusf(float v) {
    return v > 20.f ? v : log1pf(expf(v));
}

// ---------------------------------------------------------------------------
// Weight prep: cast/reorder conv weights to oc-major fp16 ("B^T" GEMM operand)
// ---------------------------------------------------------------------------
__global__ void prep_kernel(const float* __restrict__ W1, const float* __restrict__ W2,
                            const float* __restrict__ W3,
                            half_t* __restrict__ B1w, half_t* __restrict__ B2w,
                            half_t* __restrict__ B3w)
{
    const unsigned idx = blockIdx.x * 256u + threadIdx.x;
    const unsigned n2 = 768u * 6912u;                 // 5,308,416
    if (idx < n2) {
        unsigned oc = idx / 6912u;
        unsigned rem = idx - oc * 6912u;
        unsigned tap = rem / 768u;
        unsigned ic = rem - tap * 768u;
        unsigned ky = tap / 3u, kx = tap - ky * 3u;
        B2w[idx] = (half_t)W2[(((size_t)oc * 768u + ic) * 3u + ky) * 3u + kx];
    } else if (idx < n2 + 147456u) {
        unsigned i = idx - n2;
        B1w[i] = (half_t)W1[i];                       // W1 flat is already (oc,ic)
    } else if (idx < n2 + 294912u) {
        unsigned i = idx - n2 - 147456u;
        B3w[i] = (half_t)W3[i];                       // W3 flat is already (oc,ic)
    }
}

// ---------------------------------------------------------------------------
// Per-window linear attention. One block per window. Writes feat NHWC fp16.
// ---------------------------------------------------------------------------
__global__ __launch_bounds__(256, 2)
void attn_kernel(const float* __restrict__ x,
                 const float* __restrict__ Wq, const float* __restrict__ bq,
                 const float* __restrict__ Wk, const float* __restrict__ bk,
                 const float* __restrict__ Wv, const float* __restrict__ bv,
                 const float* __restrict__ Wo, const float* __restrict__ bo,
                 half_t* __restrict__ featN)
{
    __shared__ half_t xls[192 * 65];
    __shared__ float wqL[512], wkL[512], wvL[512], woL[512];
    __shared__ float bqL[8], bkL[8], bvL[8], boL[64];
    __shared__ float kls[192 * 9], vls[192 * 9];
    __shared__ float sls[64];

    const int t = threadIdx.x;
    const int blk = blockIdx.x;
    const int b = blk >> 10;
    const int n = blk & 1023;
    const int wi = n >> 5, wj = n & 31;

    for (int i = t; i < 512; i += 256) {
        wqL[i] = Wq[i]; wkL[i] = Wk[i]; wvL[i] = Wv[i]; woL[i] = Wo[i];
    }
    if (t < 8)  { bqL[t] = bq[t]; bkL[t] = bk[t]; bvL[t] = bv[t]; }
    if (t < 64) boL[t] = bo[t];

    #pragma unroll
    for (int i = 0; i < 6; ++i) {
        int idx = t + i * 256;                 // 0..1535 = (c,py)
        int c = idx >> 3, py = idx & 7;
        const float* src = x + (((size_t)b * 192 + c) * 256 + (wi * 8 + py)) * 256 + wj * 8;
        float4 v0 = *(const float4*)src;
        float4 v1 = *(const float4*)(src + 4);
        half_t* dst = &xls[c * 65 + py * 8];
        dst[0] = (half_t)v0.x; dst[1] = (half_t)v0.y; dst[2] = (half_t)v0.z; dst[3] = (half_t)v0.w;
        dst[4] = (half_t)v1.x; dst[5] = (half_t)v1.y; dst[6] = (half_t)v1.z; dst[7] = (half_t)v1.w;
    }
    __syncthreads();

    float qf[8], kf[8], vf[8];
    if (t < 192) {
        #pragma unroll
        for (int d = 0; d < 8; ++d) { qf[d] = bqL[d]; kf[d] = bkL[d]; vf[d] = bvL[d]; }
        const half_t* xr = &xls[t * 65];
        for (int p = 0; p < 64; ++p) {
            float xv = (float)xr[p];
            const float* wqp = &wqL[p * 8];
            const float* wkp = &wkL[p * 8];
            const float* wvp = &wvL[p * 8];
            #pragma unroll
            for (int d = 0; d < 8; ++d) {
                qf[d] += xv * wqp[d];
                kf[d] += xv * wkp[d];
                vf[d] += xv * wvp[d];
            }
        }
        #pragma unroll
        for (int d = 0; d < 8; ++d) {
            qf[d] = softplusf(qf[d]);
            kf[d] = softplusf(kf[d]);
            kls[t * 9 + d] = kf[d];
            vls[t * 9 + d] = vf[d];
        }
    }
    __syncthreads();
    if (t < 64) {
        int e = t >> 3, dd = t & 7;
        float s = 0.f;
        for (int c = 0; c < 192; ++c) s += kls[c * 9 + e] * vls[c * 9 + dd];
        sls[t] = s;
    }
    __syncthreads();
    if (t < 192) {
        float rf[8];
        #pragma unroll
        for (int d = 0; d < 8; ++d) {
            float s = 0.f;
            #pragma unroll
            for (int e = 0; e < 8; ++e) s += qf[e] * sls[e * 8 + d];
            rf[d] = s;
        }
        half_t* xr = &xls[t * 65];
        for (int p = 0; p < 64; ++p) {
            float a = boL[p];
            #pragma unroll
            for (int d = 0; d < 8; ++d) a += rf[d] * woL[d * 64 + p];
            xr[p] = (half_t)((float)xr[p] + a);
        }
    }
    __syncthreads();
    half_t* dst = featN + ((size_t)b * 65536 + (size_t)n * 64) * 192;
    for (int i = 0; i < 48; ++i) {
        int idx = t + i * 256;                 // 0..12287 = p*192 + c
        int p = idx / 192, c = idx - p * 192;
        dst[idx] = xls[c * 65 + p];
    }
}

// ---------------------------------------------------------------------------
// conv1: 1x1 192->768 + leaky. GEMM M=65536 (one batch), N=768, K=192.
// ---------------------------------------------------------------------------
__global__ __launch_bounds__(256, 2)
void conv1_kernel(const half_t* __restrict__ featN, const half_t* __restrict__ B1w,
                  const float* __restrict__ b1, half_t* __restrict__ h1p, int batch)
{
    __shared__ half_t As[128 * 64];
    __shared__ half_t Bs[128 * 64];
    const int t = threadIdx.x;
    const int lane = t & 63;
    const int w = t >> 6;
    const int m0 = blockIdx.x * 128;
    const int n0 = blockIdx.y * 128;
    const int wm = (w >> 1) * 64, wn = (w & 1) * 64;
    const int rbase = t >> 3;
    const int g = (t & 7) ^ (rbase & 7);
    const int ar = lane & 15, kc = lane >> 4;

    f32x4 acc[4][4];
    #pragma unroll
    for (int i = 0; i < 4; ++i)
        #pragma unroll
        for (int j = 0; j < 4; ++j) acc[i][j] = (f32x4){0.f, 0.f, 0.f, 0.f};

    const size_t mb = (size_t)batch * 65536 + m0;

    for (int s = 0; s < 3; ++s) {
        const int k0 = s * 64;
        const half_t* ga = featN + (mb + rbase) * 192 + k0 + g * 8;
        const half_t* gb = B1w + (size_t)(n0 + rbase) * 192 + k0 + g * 8;
        half_t* la = As + t * 8;
        half_t* lb = Bs + t * 8;
        #pragma unroll
        for (int i = 0; i < 4; ++i) {
            stage16(ga + (size_t)32 * i * 192, la + 2048 * i);
            stage16(gb + (size_t)32 * i * 192, lb + 2048 * i);
        }
        __syncthreads();
        #pragma unroll
        for (int kh = 0; kh < 2; ++kh) {
            f16x8 af[4], bfr[4];
            const int c = kh * 4 + kc;
            #pragma unroll
            for (int mf = 0; mf < 4; ++mf) {
                int r = wm + mf * 16 + ar;
                af[mf] = *(const f16x8*)&As[(r * 8 + (c ^ (r & 7))) * 8];
            }
            #pragma unroll
            for (int nf = 0; nf < 4; ++nf) {
                int r = wn + nf * 16 + ar;
                bfr[nf] = *(const f16x8*)&Bs[(r * 8 + (c ^ (r & 7))) * 8];
            }
            #pragma unroll
            for (int mf = 0; mf < 4; ++mf)
                #pragma unroll
                for (int nf = 0; nf < 4; ++nf)
                    acc[mf][nf] = __builtin_amdgcn_mfma_f32_16x16x32_f16(af[mf], bfr[nf], acc[mf][nf], 0, 0, 0);
        }
        __syncthreads();
    }

    const int y = m0 >> 8, x0 = m0 & 255;
    half_t* outrow = h1p + ((size_t)(y + 1) * 258 + (x0 + 1)) * 768;
    #pragma unroll
    for (int nf = 0; nf < 4; ++nf) {
        int n = n0 + wn + nf * 16 + ar;
        float bias = b1[n];
        #pragma unroll
        for (int mf = 0; mf < 4; ++mf) {
            #pragma unroll
            for (int r4 = 0; r4 < 4; ++r4) {
                int local = wm + mf * 16 + kc * 4 + r4;
                outrow[(size_t)local * 768 + n] = (half_t)leaky(acc[mf][nf][r4] + bias);
            }
        }
    }
}

// ---------------------------------------------------------------------------
// conv2 v9 = EXACT v4 (best measured: wall 2907us, conv2 670us/50.6%) with 4
// provably-redundant barriers removed per iteration (10 -> 6):
//  - ph2->ph3, ph6->ph7: ph3/ph7 have no ds_reads/stages; the ph4/ph8 stage
//    is guarded by ph3/ph7's LGKM(0) + the kept ph3->ph4 barrier.
//  - ph4/ph8 trailing: ph5/ph1 stage nothing; the next h0 overwrite (ph6/ph2)
//    is guarded by ph5/ph1's LGKM(12) (oldest-12 = boundary reads complete)
//    + the kept ph5->ph6 / ph1->ph2 barrier.
// Everything else byte-identical to v4 (reads, stages, waits, grid, swizzle).
// ---------------------------------------------------------------------------
__device__ __forceinline__ void c2_stage_A(half_t* As, int buf, int h,
    const half_t* __restrict__ h1p, int y, int kstep, int t, int cg)
{
    const int tap = kstep / 12, icc = kstep - tap * 12;
    const int ky = tap / 3, kx = tap - ky * 3;
    const int row0 = t >> 3;
    const half_t* g = h1p + ((size_t)(y + ky) * 258 + (kx + h * 128 + row0)) * 768
                      + icc * 64 + cg;
    half_t* l = As + (buf * 2 + h) * 8192 + t * 8;
    stage16(g, l);
    stage16(g + (size_t)64 * 768, l + 4096);
}

__device__ __forceinline__ void c2_stage_B(half_t* Bs, int buf, int h,
    const half_t* __restrict__ B2w, int n0, int kstep, int t, int cg)
{
    const int tap = kstep / 12, icc = kstep - tap * 12;
    const int row0 = t >> 3;
    const half_t* g = B2w + (size_t)(n0 + h * 128 + row0) * 6912
                      + tap * 768 + icc * 64 + cg;
    half_t* l = Bs + (buf * 2 + h) * 8192 + t * 8;
    stage16(g, l);
    stage16(g + (size_t)64 * 6912, l + 4096);
}

#define SBAR __builtin_amdgcn_s_barrier()
#define SB0  __builtin_amdgcn_sched_barrier(0)
#define LGKM(N) asm volatile("s_waitcnt lgkmcnt(" #N ")" ::: "memory")
#define VMC(N)  asm volatile("s_waitcnt vmcnt(" #N ")" ::: "memory")

// 8 ds_read_b128 into af[MQ] (frags for both kh of quadrant row-half MQ)
#define RDA(MQ, BUF)                                                             \
  _Pragma("unroll")                                                              \
  for (int mf = 0; mf < 4; ++mf)                                                 \
    _Pragma("unroll")                                                            \
    for (int kh = 0; kh < 2; ++kh) {                                             \
      const int lr = wm * 64 + mf * 16 + ar;                                     \
      const int ch = (kh * 4 + kc) ^ (lr & 7);                                   \
      af[MQ][mf][kh] = *(const f16x8*)&As[((BUF)*2 + (MQ))*8192 + lr*64 + ch*8]; \
    }

// 4 ds_read_b128 into bf[NQ]
#define RDB(NQ, BUF)                                                             \
  _Pragma("unroll")                                                              \
  for (int nf = 0; nf < 2; ++nf)                                                 \
    _Pragma("unroll")                                                            \
    for (int kh = 0; kh < 2; ++kh) {                                             \
      const int lc = wn * 32 + nf * 16 + ar;                                     \
      const int ch = (kh * 4 + kc) ^ (lc & 7);                                   \
      bf[NQ][nf][kh] = *(const f16x8*)&Bs[((BUF)*2 + (NQ))*8192 + lc*64 + ch*8]; \
    }

#define MMA16(MQ, NQ)                                                            \
  {                                                                              \
    __builtin_amdgcn_s_setprio(1);                                               \
    _Pragma("unroll")                                                            \
    for (int kh = 0; kh < 2; ++kh)                                               \
      _Pragma("unroll")                                                          \
      for (int mf = 0; mf < 4; ++mf)                                             \
        _Pragma("unroll")                                                        \
        for (int nf = 0; nf < 2; ++nf)                                           \
          acc[(MQ)*2+(NQ)][mf][nf] = __builtin_amdgcn_mfma_f32_16x16x32_f16(     \
              af[MQ][mf][kh], bf[NQ][nf][kh], acc[(MQ)*2+(NQ)][mf][nf], 0, 0, 0);\
    __builtin_amdgcn_s_setprio(0);                                               \
  }

__global__ __launch_bounds__(512, 2)
void conv2_kernel(const half_t* __restrict__ h1p, const half_t* __restrict__ B2w,
                  const float* __restrict__ b2, half_t* __restrict__ h2)
{
    __shared__ half_t As[4 * 8192];    // [buf][half][128][64] f16 = 64 KiB
    __shared__ half_t Bs[4 * 8192];

    const int t = threadIdx.x;
    const int lane = t & 63;
    const int w = t >> 6;
    const int wm = w >> 2, wn = w & 3;            // 2x4 wave grid inside a quadrant
    const int ar = lane & 15, kc = lane >> 4;
    const int cg = (((t & 7) ^ ((t >> 3) & 7)) << 3);  // pre-swizzled source chunk

    // v4 grid: nt innermost + XCD-chunked mtile bands.
    const int bid = blockIdx.x;
    const int xcd = bid & 7, sid = bid >> 3;      // 96 blocks per XCD
    const int wg = xcd * 96 + sid;                // 768 = 8 XCD * 96
    const int mtile = wg / 3;
    const int nt = wg - mtile * 3;
    const int y = mtile;
    const int m0 = mtile * 256;
    const int n0 = nt * 256;

    f32x4 acc[4][4][2];
    #pragma unroll
    for (int q = 0; q < 4; ++q)
        #pragma unroll
        for (int i = 0; i < 4; ++i)
            #pragma unroll
            for (int j = 0; j < 2; ++j) acc[q][i][j] = (f32x4){0.f, 0.f, 0.f, 0.f};

    f16x8 af[2][4][2];   // [MQ][mf][kh]
    f16x8 bf[2][2][2];   // [NQ][nf][kh]

    // Prologue: stage buf0<-k0, buf1<-k1 fully; drain; issue boundary reads.
    c2_stage_A(As, 0, 0, h1p, y, 0, t, cg);
    c2_stage_A(As, 0, 1, h1p, y, 0, t, cg);
    c2_stage_B(Bs, 0, 0, B2w, n0, 0, t, cg);
    c2_stage_B(Bs, 0, 1, B2w, n0, 0, t, cg);
    c2_stage_A(As, 1, 0, h1p, y, 1, t, cg);
    c2_stage_A(As, 1, 1, h1p, y, 1, t, cg);
    c2_stage_B(Bs, 1, 0, B2w, n0, 1, t, cg);
    c2_stage_B(Bs, 1, 1, B2w, n0, 1, t, cg);
    VMC(0);
    SBAR; SB0;
    RDB(0, 0); SB0;
    RDA(0, 0);

    // Steady: 53 iterations (compute kt 0..105; stage up to kt 107).
    for (int i = 0; i < 53; ++i) {
        const int k2 = 2 * i + 2;
        const int k3 = 2 * i + 3;
        // ph1 (q00 buf0): read-ahead bf1,af1 of buf0.
        RDB(1, 0); SB0;
        RDA(1, 0);
        LGKM(12); SB0;
        MMA16(0, 0);
        SBAR;                                   // protects ph2's h0 stage
        // ph2 (q01 buf0): stage A0h0,B0h0 <- k2.
        c2_stage_A(As, 0, 0, h1p, y, k2, t, cg);
        c2_stage_B(Bs, 0, 0, B2w, n0, k2, t, cg);
        LGKM(8); SB0;
        MMA16(0, 1);
        // (barrier removed: ph3 has no LDS writes/reads to order)
        // ph3 (q11 buf0).
        LGKM(0); SB0;
        MMA16(1, 1);
        SBAR;                                   // protects ph4's h1 stage
        // ph4 (q10 buf0): stage A0h1,B0h1 <- k2; vmcnt(8); post-reads buf1.
        c2_stage_A(As, 0, 1, h1p, y, k2, t, cg);
        c2_stage_B(Bs, 0, 1, B2w, n0, k2, t, cg);
        VMC(8);
        SBAR; SB0;                              // all waves drained -> buf1 ready
        MMA16(1, 0);
        SB0;
        RDB(0, 1); SB0;
        RDA(0, 1);
        // (trailing barrier removed: ph5 stages nothing; ph6's stage is
        //  guarded by ph5's LGKM(12) + the ph5->ph6 barrier)
        // ph5 (q00 buf1): read-ahead bf1,af1 of buf1.
        RDB(1, 1); SB0;
        RDA(1, 1);
        LGKM(12); SB0;
        MMA16(0, 0);
        SBAR;                                   // protects ph6's h0 stage
        // ph6 (q01 buf1): stage A1h0,B1h0 <- k3.
        c2_stage_A(As, 1, 0, h1p, y, k3, t, cg);
        c2_stage_B(Bs, 1, 0, B2w, n0, k3, t, cg);
        LGKM(8); SB0;
        MMA16(0, 1);
        // (barrier removed)
        // ph7 (q11 buf1).
        LGKM(0); SB0;
        MMA16(1, 1);
        SBAR;                                   // protects ph8's h1 stage
        // ph8 (q10 buf1): stage A1h1,B1h1 <- k3; vmcnt(8); post-reads buf0 next.
        c2_stage_A(As, 1, 1, h1p, y, k3, t, cg);
        c2_stage_B(Bs, 1, 1, B2w, n0, k3, t, cg);
        VMC(8);
        SBAR; SB0;                              // all waves drained -> buf0 ready
        MMA16(1, 0);
        SB0;
        RDB(0, 0); SB0;
        RDA(0, 0);
        // (trailing barrier removed)
    }
    // Tail (kt 106,107): no stages, no next-buffer reads.
    {
        // ph1
        RDB(1, 0); SB0;
        RDA(1, 0);
        LGKM(12); SB0;
        MMA16(0, 0);
        SBAR;
        // ph2
        LGKM(8); SB0;
        MMA16(0, 1);
        // (barrier removed)
        // ph3
        LGKM(0); SB0;
        MMA16(1, 1);
        SBAR;
        // ph4: drain all remaining stages (prev ph6/ph8), then buf1 reads.
        VMC(0);
        SBAR; SB0;
        MMA16(1, 0);
        SB0;
        RDB(0, 1); SB0;
        RDA(0, 1);
        // (trailing barrier removed)
        // ph5
        RDB(1, 1); SB0;
        RDA(1, 1);
        LGKM(12); SB0;
        MMA16(0, 0);
        SBAR;
        // ph6
        LGKM(8); SB0;
        MMA16(0, 1);
        // (barrier removed)
        // ph7
        LGKM(0); SB0;
        MMA16(1, 1);
        SBAR;
        // ph8
        MMA16(1, 0);
    }

    // Epilogue: bias + leaky, write NHWC fp16.
    #pragma unroll
    for (int q = 0; q < 4; ++q) {
        const int mq = q >> 1, nq = q & 1;
        #pragma unroll
        for (int nf = 0; nf < 2; ++nf) {
            const int col = n0 + nq * 128 + wn * 32 + nf * 16 + ar;
            const float bias = b2[col];
            #pragma unroll
            for (int mf = 0; mf < 4; ++mf) {
                const int row = m0 + mq * 128 + wm * 64 + mf * 16 + kc * 4;
                half_t* op = h2 + (size_t)row * 768 + col;
                #pragma unroll
                for (int r4 = 0; r4 < 4; ++r4)
                    op[(size_t)r4 * 768] = (half_t)leaky(acc[q][mf][nf][r4] + bias);
            }
        }
    }
}

// ---------------------------------------------------------------------------
// conv3: 1x1 768->192 + leaky. GEMM M=65536 (one batch), N=192, K=768.
// ---------------------------------------------------------------------------
__global__ __launch_bounds__(256, 2)
void conv3_kernel(const half_t* __restrict__ h2, const half_t* __restrict__ B3w,
                  const float* __restrict__ b3, float* __restrict__ out, int batch)
{
    __shared__ half_t As[128 * 64];
    __shared__ half_t Bs[192 * 64];
    const int t = threadIdx.x;
    const int lane = t & 63;
    const int w = t >> 6;
    const int m0 = blockIdx.x * 128;
    const int wm = (w >> 1) * 64;
    const int wn = (w & 1) * 96;
    const int rbase = t >> 3;
    const int g = (t & 7) ^ (rbase & 7);
    const int ar = lane & 15, kc = lane >> 4;

    f32x4 acc[4][6];
    #pragma unroll
    for (int i = 0; i < 4; ++i)
        #pragma unroll
        for (int j = 0; j < 6; ++j) acc[i][j] = (f32x4){0.f, 0.f, 0.f, 0.f};

    for (int s = 0; s < 12; ++s) {
        const int k0 = s * 64;
        const half_t* ga = h2 + (size_t)(m0 + rbase) * 768 + k0 + g * 8;
        const half_t* gb = B3w + (size_t)rbase * 768 + k0 + g * 8;
        half_t* la = As + t * 8;
        half_t* lb = Bs + t * 8;
        #pragma unroll
        for (int i = 0; i < 4; ++i) stage16(ga + (size_t)32 * i * 768, la + 2048 * i);
        #pragma unroll
        for (int i = 0; i < 6; ++i) stage16(gb + (size_t)32 * i * 768, lb + 2048 * i);
        __syncthreads();
        #pragma unroll
        for (int kh = 0; kh < 2; ++kh) {
            f16x8 af[4], bfr[6];
            const int c = kh * 4 + kc;
            #pragma unroll
            for (int mf = 0; mf < 4; ++mf) {
                int r = wm + mf * 16 + ar;
                af[mf] = *(const f16x8*)&As[(r * 8 + (c ^ (r & 7))) * 8];
            }
            #pragma unroll
            for (int nf = 0; nf < 6; ++nf) {
                int r = wn + nf * 16 + ar;
                bfr[nf] = *(const f16x8*)&Bs[(r * 8 + (c ^ (r & 7))) * 8];
            }
            #pragma unroll
            for (int mf = 0; mf < 4; ++mf)
                #pragma unroll
                for (int nf = 0; nf < 6; ++nf)
                    acc[mf][nf] = __builtin_amdgcn_mfma_f32_16x16x32_f16(af[mf], bfr[nf], acc[mf][nf], 0, 0, 0);
        }
        __syncthreads();
    }

    #pragma unroll
    for (int nf = 0; nf < 6; ++nf) {
        int n = wn + nf * 16 + ar;
        float bias = b3[n];
        float* op = out + ((size_t)batch * 192 + n) * 65536 + m0;
        #pragma unroll
        for (int mf = 0; mf < 4; ++mf) {
            int local = wm + mf * 16 + kc * 4;
            f32x4 v;
            #pragma unroll
            for (int r4 = 0; r4 < 4; ++r4) v[r4] = leaky(acc[mf][nf][r4] + bias);
            *(f32x4*)(op + local) = v;
        }
    }
}

// ---------------------------------------------------------------------------
extern "C" void kernel_launch(void* const* d_in, const int* in_sizes, int n_in,
                              void* d_out, int out_size, void* d_ws, size_t ws_size,
                              hipStream_t stream)
{
    const float* x  = (const float*)d_in[0];
    const float* Wq = (const float*)d_in[1];
    const float* bq = (const float*)d_in[2];
    const float* Wk = (const float*)d_in[3];
    const float* bk = (const float*)d_in[4];
    const float* Wv = (const float*)d_in[5];
    const float* bv = (const float*)d_in[6];
    const float* Wo = (const float*)d_in[7];
    const float* bo = (const float*)d_in[8];
    const float* W1 = (const float*)d_in[9];
    const float* b1 = (const float*)d_in[10];
    const float* W2 = (const float*)d_in[11];
    const float* b2 = (const float*)d_in[12];
    const float* W3 = (const float*)d_in[13];
    const float* b3 = (const float*)d_in[14];

    char* ws = (char*)d_ws;
    const size_t OFF_B1   = 0;
    const size_t OFF_B3   = 294912;
    const size_t OFF_B2   = 589824;
    const size_t OFF_FEAT = 11206656;
    const size_t OFF_H1P  = 111869952;
    const size_t OFF_H2   = 214124544;
    const size_t WS_NEED  = 314787840;
    if (ws_size < WS_NEED) return;

    half_t* B1w   = (half_t*)(ws + OFF_B1);
    half_t* B3w   = (half_t*)(ws + OFF_B3);
    half_t* B2w   = (half_t*)(ws + OFF_B2);
    half_t* featN = (half_t*)(ws + OFF_FEAT);
    half_t* h1p   = (half_t*)(ws + OFF_H1P);
    half_t* h2    = (half_t*)(ws + OFF_H2);

    hipMemsetAsync(h1p, 0, 102254592, stream);
    prep_kernel<<<21888, 256, 0, stream>>>(W1, W2, W3, B1w, B2w, B3w);
    attn_kernel<<<4096, 256, 0, stream>>>(x, Wq, bq, Wk, bk, Wv, bv, Wo, bo, featN);

    for (int b = 0; b < 4; ++b) {
        conv1_kernel<<<dim3(512, 6), 256, 0, stream>>>(featN, B1w, b1, h1p, b);
        conv2_kernel<<<768, 512, 0, stream>>>(h1p, B2w, b2, h2);
        conv3_kernel<<<dim3(512, 1), 256, 0, stream>>>(h2, B3w, b3, (float*)d_out, b);
    }
}

// Round 10
// 2799.429 us; speedup vs baseline: 1.1842x; 1.0272x over previous
//
#include <hip/hip_runtime.h>
#include <stdint.h>
#include <math.h>

typedef _Float16 half_t;
typedef _Float16 f16x8 __attribute__((ext_vector_type(8)));
typedef float f32x4 __attribute__((ext_vector_type(4)));

#define SLOPE 0.01f

__device__ inline float leaky(float v) { return v > 0.f ? v : SLOPE * v; }

__device__ inline void stage16(const half_t* g, half_t* l) {
    __builtin_amdgcn_global_load_lds(
        (const __attribute__((address_space(1))) unsigned int*)g,
        (__attribute__((address_space(3))) unsigned int*)l, 16, 0, 0);
}

__device__ inline float softplusf(float v) {
    return v > 20.f ? v : log1pf(expf(v));
}

// ---------------------------------------------------------------------------
// Weight prep: cast/reorder conv weights to oc-major fp16 ("B^T" GEMM operand)
// ---------------------------------------------------------------------------
__global__ void prep_kernel(const float* __restrict__ W1, const float* __restrict__ W2,
                            const float* __restrict__ W3,
                            half_t* __restrict__ B1w, half_t* __restrict__ B2w,
                            half_t* __restrict__ B3w)
{
    const unsigned idx = blockIdx.x * 256u + threadIdx.x;
    const unsigned n2 = 768u * 6912u;                 // 5,308,416
    if (idx < n2) {
        unsigned oc = idx / 6912u;
        unsigned rem = idx - oc * 6912u;
        unsigned tap = rem / 768u;
        unsigned ic = rem - tap * 768u;
        unsigned ky = tap / 3u, kx = tap - ky * 3u;
        B2w[idx] = (half_t)W2[(((size_t)oc * 768u + ic) * 3u + ky) * 3u + kx];
    } else if (idx < n2 + 147456u) {
        unsigned i = idx - n2;
        B1w[i] = (half_t)W1[i];                       // W1 flat is already (oc,ic)
    } else if (idx < n2 + 294912u) {
        unsigned i = idx - n2 - 147456u;
        B3w[i] = (half_t)W3[i];                       // W3 flat is already (oc,ic)
    }
}

// ---------------------------------------------------------------------------
// Per-window linear attention. One block per window. Writes feat NHWC fp16.
// ---------------------------------------------------------------------------
__global__ __launch_bounds__(256, 2)
void attn_kernel(const float* __restrict__ x,
                 const float* __restrict__ Wq, const float* __restrict__ bq,
                 const float* __restrict__ Wk, const float* __restrict__ bk,
                 const float* __restrict__ Wv, const float* __restrict__ bv,
                 const float* __restrict__ Wo, const float* __restrict__ bo,
                 half_t* __restrict__ featN)
{
    __shared__ half_t xls[192 * 65];
    __shared__ float wqL[512], wkL[512], wvL[512], woL[512];
    __shared__ float bqL[8], bkL[8], bvL[8], boL[64];
    __shared__ float kls[192 * 9], vls[192 * 9];
    __shared__ float sls[64];

    const int t = threadIdx.x;
    const int blk = blockIdx.x;
    const int b = blk >> 10;
    const int n = blk & 1023;
    const int wi = n >> 5, wj = n & 31;

    for (int i = t; i < 512; i += 256) {
        wqL[i] = Wq[i]; wkL[i] = Wk[i]; wvL[i] = Wv[i]; woL[i] = Wo[i];
    }
    if (t < 8)  { bqL[t] = bq[t]; bkL[t] = bk[t]; bvL[t] = bv[t]; }
    if (t < 64) boL[t] = bo[t];

    #pragma unroll
    for (int i = 0; i < 6; ++i) {
        int idx = t + i * 256;                 // 0..1535 = (c,py)
        int c = idx >> 3, py = idx & 7;
        const float* src = x + (((size_t)b * 192 + c) * 256 + (wi * 8 + py)) * 256 + wj * 8;
        float4 v0 = *(const float4*)src;
        float4 v1 = *(const float4*)(src + 4);
        half_t* dst = &xls[c * 65 + py * 8];
        dst[0] = (half_t)v0.x; dst[1] = (half_t)v0.y; dst[2] = (half_t)v0.z; dst[3] = (half_t)v0.w;
        dst[4] = (half_t)v1.x; dst[5] = (half_t)v1.y; dst[6] = (half_t)v1.z; dst[7] = (half_t)v1.w;
    }
    __syncthreads();

    float qf[8], kf[8], vf[8];
    if (t < 192) {
        #pragma unroll
        for (int d = 0; d < 8; ++d) { qf[d] = bqL[d]; kf[d] = bkL[d]; vf[d] = bvL[d]; }
        const half_t* xr = &xls[t * 65];
        for (int p = 0; p < 64; ++p) {
            float xv = (float)xr[p];
            const float* wqp = &wqL[p * 8];
            const float* wkp = &wkL[p * 8];
            const float* wvp = &wvL[p * 8];
            #pragma unroll
            for (int d = 0; d < 8; ++d) {
                qf[d] += xv * wqp[d];
                kf[d] += xv * wkp[d];
                vf[d] += xv * wvp[d];
            }
        }
        #pragma unroll
        for (int d = 0; d < 8; ++d) {
            qf[d] = softplusf(qf[d]);
            kf[d] = softplusf(kf[d]);
            kls[t * 9 + d] = kf[d];
            vls[t * 9 + d] = vf[d];
        }
    }
    __syncthreads();
    if (t < 64) {
        int e = t >> 3, dd = t & 7;
        float s = 0.f;
        for (int c = 0; c < 192; ++c) s += kls[c * 9 + e] * vls[c * 9 + dd];
        sls[t] = s;
    }
    __syncthreads();
    if (t < 192) {
        float rf[8];
        #pragma unroll
        for (int d = 0; d < 8; ++d) {
            float s = 0.f;
            #pragma unroll
            for (int e = 0; e < 8; ++e) s += qf[e] * sls[e * 8 + d];
            rf[d] = s;
        }
        half_t* xr = &xls[t * 65];
        for (int p = 0; p < 64; ++p) {
            float a = boL[p];
            #pragma unroll
            for (int d = 0; d < 8; ++d) a += rf[d] * woL[d * 64 + p];
            xr[p] = (half_t)((float)xr[p] + a);
        }
    }
    __syncthreads();
    half_t* dst = featN + ((size_t)b * 65536 + (size_t)n * 64) * 192;
    for (int i = 0; i < 48; ++i) {
        int idx = t + i * 256;                 // 0..12287 = p*192 + c
        int p = idx / 192, c = idx - p * 192;
        dst[idx] = xls[c * 65 + p];
    }
}

// ---------------------------------------------------------------------------
// conv1: 1x1 192->768 + leaky. GEMM M=65536 (one batch), N=768, K=192.
// ---------------------------------------------------------------------------
__global__ __launch_bounds__(256, 2)
void conv1_kernel(const half_t* __restrict__ featN, const half_t* __restrict__ B1w,
                  const float* __restrict__ b1, half_t* __restrict__ h1p, int batch)
{
    __shared__ half_t As[128 * 64];
    __shared__ half_t Bs[128 * 64];
    const int t = threadIdx.x;
    const int lane = t & 63;
    const int w = t >> 6;
    const int m0 = blockIdx.x * 128;
    const int n0 = blockIdx.y * 128;
    const int wm = (w >> 1) * 64, wn = (w & 1) * 64;
    const int rbase = t >> 3;
    const int g = (t & 7) ^ (rbase & 7);
    const int ar = lane & 15, kc = lane >> 4;

    f32x4 acc[4][4];
    #pragma unroll
    for (int i = 0; i < 4; ++i)
        #pragma unroll
        for (int j = 0; j < 4; ++j) acc[i][j] = (f32x4){0.f, 0.f, 0.f, 0.f};

    const size_t mb = (size_t)batch * 65536 + m0;

    for (int s = 0; s < 3; ++s) {
        const int k0 = s * 64;
        const half_t* ga = featN + (mb + rbase) * 192 + k0 + g * 8;
        const half_t* gb = B1w + (size_t)(n0 + rbase) * 192 + k0 + g * 8;
        half_t* la = As + t * 8;
        half_t* lb = Bs + t * 8;
        #pragma unroll
        for (int i = 0; i < 4; ++i) {
            stage16(ga + (size_t)32 * i * 192, la + 2048 * i);
            stage16(gb + (size_t)32 * i * 192, lb + 2048 * i);
        }
        __syncthreads();
        #pragma unroll
        for (int kh = 0; kh < 2; ++kh) {
            f16x8 af[4], bfr[4];
            const int c = kh * 4 + kc;
            #pragma unroll
            for (int mf = 0; mf < 4; ++mf) {
                int r = wm + mf * 16 + ar;
                af[mf] = *(const f16x8*)&As[(r * 8 + (c ^ (r & 7))) * 8];
            }
            #pragma unroll
            for (int nf = 0; nf < 4; ++nf) {
                int r = wn + nf * 16 + ar;
                bfr[nf] = *(const f16x8*)&Bs[(r * 8 + (c ^ (r & 7))) * 8];
            }
            #pragma unroll
            for (int mf = 0; mf < 4; ++mf)
                #pragma unroll
                for (int nf = 0; nf < 4; ++nf)
                    acc[mf][nf] = __builtin_amdgcn_mfma_f32_16x16x32_f16(af[mf], bfr[nf], acc[mf][nf], 0, 0, 0);
        }
        __syncthreads();
    }

    const int y = m0 >> 8, x0 = m0 & 255;
    half_t* outrow = h1p + ((size_t)(y + 1) * 258 + (x0 + 1)) * 768;
    #pragma unroll
    for (int nf = 0; nf < 4; ++nf) {
        int n = n0 + wn + nf * 16 + ar;
        float bias = b1[n];
        #pragma unroll
        for (int mf = 0; mf < 4; ++mf) {
            #pragma unroll
            for (int r4 = 0; r4 < 4; ++r4) {
                int local = wm + mf * 16 + kc * 4 + r4;
                outrow[(size_t)local * 768 + n] = (half_t)leaky(acc[mf][nf][r4] + bias);
            }
        }
    }
}

// ---------------------------------------------------------------------------
// conv2 v10 = EXACT v9 (wall 2876us, conv2 650us/52.2%) with ONE change:
// K-traversal order flipped to ic-chunk OUTER, tap INNER
// (tap = kstep % 9, icc = kstep / 9). 9 consecutive K-steps now touch the
// same three h1p row-segments (y..y+2, +-1 px) and one 64-ic slice
// (~99 KB unique/9 steps/block; ~2 MB/XCD after nt-sharing -> L2-resident),
// so A staging hits L2 instead of re-fetching HBM once per ky tap.
// fp32 accumulation makes the order change numerically benign.
// Everything else byte-identical to v9.
// ---------------------------------------------------------------------------
__device__ __forceinline__ void c2_stage_A(half_t* As, int buf, int h,
    const half_t* __restrict__ h1p, int y, int kstep, int t, int cg)
{
    const int icc = kstep / 9, tap = kstep - icc * 9;   // tap inner (v10)
    const int ky = tap / 3, kx = tap - ky * 3;
    const int row0 = t >> 3;
    const half_t* g = h1p + ((size_t)(y + ky) * 258 + (kx + h * 128 + row0)) * 768
                      + icc * 64 + cg;
    half_t* l = As + (buf * 2 + h) * 8192 + t * 8;
    stage16(g, l);
    stage16(g + (size_t)64 * 768, l + 4096);
}

__device__ __forceinline__ void c2_stage_B(half_t* Bs, int buf, int h,
    const half_t* __restrict__ B2w, int n0, int kstep, int t, int cg)
{
    const int icc = kstep / 9, tap = kstep - icc * 9;   // tap inner (v10)
    const int row0 = t >> 3;
    const half_t* g = B2w + (size_t)(n0 + h * 128 + row0) * 6912
                      + tap * 768 + icc * 64 + cg;
    half_t* l = Bs + (buf * 2 + h) * 8192 + t * 8;
    stage16(g, l);
    stage16(g + (size_t)64 * 6912, l + 4096);
}

#define SBAR __builtin_amdgcn_s_barrier()
#define SB0  __builtin_amdgcn_sched_barrier(0)
#define LGKM(N) asm volatile("s_waitcnt lgkmcnt(" #N ")" ::: "memory")
#define VMC(N)  asm volatile("s_waitcnt vmcnt(" #N ")" ::: "memory")

// 8 ds_read_b128 into af[MQ] (frags for both kh of quadrant row-half MQ)
#define RDA(MQ, BUF)                                                             \
  _Pragma("unroll")                                                              \
  for (int mf = 0; mf < 4; ++mf)                                                 \
    _Pragma("unroll")                                                            \
    for (int kh = 0; kh < 2; ++kh) {                                             \
      const int lr = wm * 64 + mf * 16 + ar;                                     \
      const int ch = (kh * 4 + kc) ^ (lr & 7);                                   \
      af[MQ][mf][kh] = *(const f16x8*)&As[((BUF)*2 + (MQ))*8192 + lr*64 + ch*8]; \
    }

// 4 ds_read_b128 into bf[NQ]
#define RDB(NQ, BUF)                                                             \
  _Pragma("unroll")                                                              \
  for (int nf = 0; nf < 2; ++nf)                                                 \
    _Pragma("unroll")                                                            \
    for (int kh = 0; kh < 2; ++kh) {                                             \
      const int lc = wn * 32 + nf * 16 + ar;                                     \
      const int ch = (kh * 4 + kc) ^ (lc & 7);                                   \
      bf[NQ][nf][kh] = *(const f16x8*)&Bs[((BUF)*2 + (NQ))*8192 + lc*64 + ch*8]; \
    }

#define MMA16(MQ, NQ)                                                            \
  {                                                                              \
    __builtin_amdgcn_s_setprio(1);                                               \
    _Pragma("unroll")                                                            \
    for (int kh = 0; kh < 2; ++kh)                                               \
      _Pragma("unroll")                                                          \
      for (int mf = 0; mf < 4; ++mf)                                             \
        _Pragma("unroll")                                                        \
        for (int nf = 0; nf < 2; ++nf)                                           \
          acc[(MQ)*2+(NQ)][mf][nf] = __builtin_amdgcn_mfma_f32_16x16x32_f16(     \
              af[MQ][mf][kh], bf[NQ][nf][kh], acc[(MQ)*2+(NQ)][mf][nf], 0, 0, 0);\
    __builtin_amdgcn_s_setprio(0);                                               \
  }

__global__ __launch_bounds__(512, 2)
void conv2_kernel(const half_t* __restrict__ h1p, const half_t* __restrict__ B2w,
                  const float* __restrict__ b2, half_t* __restrict__ h2)
{
    __shared__ half_t As[4 * 8192];    // [buf][half][128][64] f16 = 64 KiB
    __shared__ half_t Bs[4 * 8192];

    const int t = threadIdx.x;
    const int lane = t & 63;
    const int w = t >> 6;
    const int wm = w >> 2, wn = w & 3;            // 2x4 wave grid inside a quadrant
    const int ar = lane & 15, kc = lane >> 4;
    const int cg = (((t & 7) ^ ((t >> 3) & 7)) << 3);  // pre-swizzled source chunk

    // v4 grid: nt innermost + XCD-chunked mtile bands.
    const int bid = blockIdx.x;
    const int xcd = bid & 7, sid = bid >> 3;      // 96 blocks per XCD
    const int wg = xcd * 96 + sid;                // 768 = 8 XCD * 96
    const int mtile = wg / 3;
    const int nt = wg - mtile * 3;
    const int y = mtile;
    const int m0 = mtile * 256;
    const int n0 = nt * 256;

    f32x4 acc[4][4][2];
    #pragma unroll
    for (int q = 0; q < 4; ++q)
        #pragma unroll
        for (int i = 0; i < 4; ++i)
            #pragma unroll
            for (int j = 0; j < 2; ++j) acc[q][i][j] = (f32x4){0.f, 0.f, 0.f, 0.f};

    f16x8 af[2][4][2];   // [MQ][mf][kh]
    f16x8 bf[2][2][2];   // [NQ][nf][kh]

    // Prologue: stage buf0<-k0, buf1<-k1 fully; drain; issue boundary reads.
    c2_stage_A(As, 0, 0, h1p, y, 0, t, cg);
    c2_stage_A(As, 0, 1, h1p, y, 0, t, cg);
    c2_stage_B(Bs, 0, 0, B2w, n0, 0, t, cg);
    c2_stage_B(Bs, 0, 1, B2w, n0, 0, t, cg);
    c2_stage_A(As, 1, 0, h1p, y, 1, t, cg);
    c2_stage_A(As, 1, 1, h1p, y, 1, t, cg);
    c2_stage_B(Bs, 1, 0, B2w, n0, 1, t, cg);
    c2_stage_B(Bs, 1, 1, B2w, n0, 1, t, cg);
    VMC(0);
    SBAR; SB0;
    RDB(0, 0); SB0;
    RDA(0, 0);

    // Steady: 53 iterations (compute kt 0..105; stage up to kt 107).
    for (int i = 0; i < 53; ++i) {
        const int k2 = 2 * i + 2;
        const int k3 = 2 * i + 3;
        // ph1 (q00 buf0): read-ahead bf1,af1 of buf0.
        RDB(1, 0); SB0;
        RDA(1, 0);
        LGKM(12); SB0;
        MMA16(0, 0);
        SBAR;                                   // protects ph2's h0 stage
        // ph2 (q01 buf0): stage A0h0,B0h0 <- k2.
        c2_stage_A(As, 0, 0, h1p, y, k2, t, cg);
        c2_stage_B(Bs, 0, 0, B2w, n0, k2, t, cg);
        LGKM(8); SB0;
        MMA16(0, 1);
        // (barrier removed: ph3 has no LDS writes/reads to order)
        // ph3 (q11 buf0).
        LGKM(0); SB0;
        MMA16(1, 1);
        SBAR;                                   // protects ph4's h1 stage
        // ph4 (q10 buf0): stage A0h1,B0h1 <- k2; vmcnt(8); post-reads buf1.
        c2_stage_A(As, 0, 1, h1p, y, k2, t, cg);
        c2_stage_B(Bs, 0, 1, B2w, n0, k2, t, cg);
        VMC(8);
        SBAR; SB0;                              // all waves drained -> buf1 ready
        MMA16(1, 0);
        SB0;
        RDB(0, 1); SB0;
        RDA(0, 1);
        // (trailing barrier removed)
        // ph5 (q00 buf1): read-ahead bf1,af1 of buf1.
        RDB(1, 1); SB0;
        RDA(1, 1);
        LGKM(12); SB0;
        MMA16(0, 0);
        SBAR;                                   // protects ph6's h0 stage
        // ph6 (q01 buf1): stage A1h0,B1h0 <- k3.
        c2_stage_A(As, 1, 0, h1p, y, k3, t, cg);
        c2_stage_B(Bs, 1, 0, B2w, n0, k3, t, cg);
        LGKM(8); SB0;
        MMA16(0, 1);
        // (barrier removed)
        // ph7 (q11 buf1).
        LGKM(0); SB0;
        MMA16(1, 1);
        SBAR;                                   // protects ph8's h1 stage
        // ph8 (q10 buf1): stage A1h1,B1h1 <- k3; vmcnt(8); post-reads buf0 next.
        c2_stage_A(As, 1, 1, h1p, y, k3, t, cg);
        c2_stage_B(Bs, 1, 1, B2w, n0, k3, t, cg);
        VMC(8);
        SBAR; SB0;                              // all waves drained -> buf0 ready
        MMA16(1, 0);
        SB0;
        RDB(0, 0); SB0;
        RDA(0, 0);
        // (trailing barrier removed)
    }
    // Tail (kt 106,107): no stages, no next-buffer reads.
    {
        // ph1
        RDB(1, 0); SB0;
        RDA(1, 0);
        LGKM(12); SB0;
        MMA16(0, 0);
        SBAR;
        // ph2
        LGKM(8); SB0;
        MMA16(0, 1);
        // (barrier removed)
        // ph3
        LGKM(0); SB0;
        MMA16(1, 1);
        SBAR;
        // ph4: drain all remaining stages (prev ph6/ph8), then buf1 reads.
        VMC(0);
        SBAR; SB0;
        MMA16(1, 0);
        SB0;
        RDB(0, 1); SB0;
        RDA(0, 1);
        // (trailing barrier removed)
        // ph5
        RDB(1, 1); SB0;
        RDA(1, 1);
        LGKM(12); SB0;
        MMA16(0, 0);
        SBAR;
        // ph6
        LGKM(8); SB0;
        MMA16(0, 1);
        // (barrier removed)
        // ph7
        LGKM(0); SB0;
        MMA16(1, 1);
        SBAR;
        // ph8
        MMA16(1, 0);
    }

    // Epilogue: bias + leaky, write NHWC fp16.
    #pragma unroll
    for (int q = 0; q < 4; ++q) {
        const int mq = q >> 1, nq = q & 1;
        #pragma unroll
        for (int nf = 0; nf < 2; ++nf) {
            const int col = n0 + nq * 128 + wn * 32 + nf * 16 + ar;
            const float bias = b2[col];
            #pragma unroll
            for (int mf = 0; mf < 4; ++mf) {
                const int row = m0 + mq * 128 + wm * 64 + mf * 16 + kc * 4;
                half_t* op = h2 + (size_t)row * 768 + col;
                #pragma unroll
                for (int r4 = 0; r4 < 4; ++r4)
                    op[(size_t)r4 * 768] = (half_t)leaky(acc[q][mf][nf][r4] + bias);
            }
        }
    }
}

// ---------------------------------------------------------------------------
// conv3: 1x1 768->192 + leaky. GEMM M=65536 (one batch), N=192, K=768.
// ---------------------------------------------------------------------------
__global__ __launch_bounds__(256, 2)
void conv3_kernel(const half_t* __restrict__ h2, const half_t* __restrict__ B3w,
                  const float* __restrict__ b3, float* __restrict__ out, int batch)
{
    __shared__ half_t As[128 * 64];
    __shared__ half_t Bs[192 * 64];
    const int t = threadIdx.x;
    const int lane = t & 63;
    const int w = t >> 6;
    const int m0 = blockIdx.x * 128;
    const int wm = (w >> 1) * 64;
    const int wn = (w & 1) * 96;
    const int rbase = t >> 3;
    const int g = (t & 7) ^ (rbase & 7);
    const int ar = lane & 15, kc = lane >> 4;

    f32x4 acc[4][6];
    #pragma unroll
    for (int i = 0; i < 4; ++i)
        #pragma unroll
        for (int j = 0; j < 6; ++j) acc[i][j] = (f32x4){0.f, 0.f, 0.f, 0.f};

    for (int s = 0; s < 12; ++s) {
        const int k0 = s * 64;
        const half_t* ga = h2 + (size_t)(m0 + rbase) * 768 + k0 + g * 8;
        const half_t* gb = B3w + (size_t)rbase * 768 + k0 + g * 8;
        half_t* la = As + t * 8;
        half_t* lb = Bs + t * 8;
        #pragma unroll
        for (int i = 0; i < 4; ++i) stage16(ga + (size_t)32 * i * 768, la + 2048 * i);
        #pragma unroll
        for (int i = 0; i < 6; ++i) stage16(gb + (size_t)32 * i * 768, lb + 2048 * i);
        __syncthreads();
        #pragma unroll
        for (int kh = 0; kh < 2; ++kh) {
            f16x8 af[4], bfr[6];
            const int c = kh * 4 + kc;
            #pragma unroll
            for (int mf = 0; mf < 4; ++mf) {
                int r = wm + mf * 16 + ar;
                af[mf] = *(const f16x8*)&As[(r * 8 + (c ^ (r & 7))) * 8];
            }
            #pragma unroll
            for (int nf = 0; nf < 6; ++nf) {
                int r = wn + nf * 16 + ar;
                bfr[nf] = *(const f16x8*)&Bs[(r * 8 + (c ^ (r & 7))) * 8];
            }
            #pragma unroll
            for (int mf = 0; mf < 4; ++mf)
                #pragma unroll
                for (int nf = 0; nf < 6; ++nf)
                    acc[mf][nf] = __builtin_amdgcn_mfma_f32_16x16x32_f16(af[mf], bfr[nf], acc[mf][nf], 0, 0, 0);
        }
        __syncthreads();
    }

    #pragma unroll
    for (int nf = 0; nf < 6; ++nf) {
        int n = wn + nf * 16 + ar;
        float bias = b3[n];
        float* op = out + ((size_t)batch * 192 + n) * 65536 + m0;
        #pragma unroll
        for (int mf = 0; mf < 4; ++mf) {
            int local = wm + mf * 16 + kc * 4;
            f32x4 v;
            #pragma unroll
            for (int r4 = 0; r4 < 4; ++r4) v[r4] = leaky(acc[mf][nf][r4] + bias);
            *(f32x4*)(op + local) = v;
        }
    }
}

// ---------------------------------------------------------------------------
extern "C" void kernel_launch(void* const* d_in, const int* in_sizes, int n_in,
                              void* d_out, int out_size, void* d_ws, size_t ws_size,
                              hipStream_t stream)
{
    const float* x  = (const float*)d_in[0];
    const float* Wq = (const float*)d_in[1];
    const float* bq = (const float*)d_in[2];
    const float* Wk = (const float*)d_in[3];
    const float* bk = (const float*)d_in[4];
    const float* Wv = (const float*)d_in[5];
    const float* bv = (const float*)d_in[6];
    const float* Wo = (const float*)d_in[7];
    const float* bo = (const float*)d_in[8];
    const float* W1 = (const float*)d_in[9];
    const float* b1 = (const float*)d_in[10];
    const float* W2 = (const float*)d_in[11];
    const float* b2 = (const float*)d_in[12];
    const float* W3 = (const float*)d_in[13];
    const float* b3 = (const float*)d_in[14];

    char* ws = (char*)d_ws;
    const size_t OFF_B1   = 0;
    const size_t OFF_B3   = 294912;
    const size_t OFF_B2   = 589824;
    const size_t OFF_FEAT = 11206656;
    const size_t OFF_H1P  = 111869952;
    const size_t OFF_H2   = 214124544;
    const size_t WS_NEED  = 314787840;
    if (ws_size < WS_NEED) return;

    half_t* B1w   = (half_t*)(ws + OFF_B1);
    half_t* B3w   = (half_t*)(ws + OFF_B3);
    half_t* B2w   = (half_t*)(ws + OFF_B2);
    half_t* featN = (half_t*)(ws + OFF_FEAT);
    half_t* h1p   = (half_t*)(ws + OFF_H1P);
    half_t* h2    = (half_t*)(ws + OFF_H2);

    hipMemsetAsync(h1p, 0, 102254592, stream);
    prep_kernel<<<21888, 256, 0, stream>>>(W1, W2, W3, B1w, B2w, B3w);
    attn_kernel<<<4096, 256, 0, stream>>>(x, Wq, bq, Wk, bk, Wv, bv, Wo, bo, featN);

    for (int b = 0; b < 4; ++b) {
        conv1_kernel<<<dim3(512, 6), 256, 0, stream>>>(featN, B1w, b1, h1p, b);
        conv2_kernel<<<768, 512, 0, stream>>>(h1p, B2w, b2, h2);
        conv3_kernel<<<dim3(512, 1), 256, 0, stream>>>(h2, B3w, b3, (float*)d_out, b);
    }
}

// Round 11
// 2784.709 us; speedup vs baseline: 1.1905x; 1.0053x over previous
//
#include <hip/hip_runtime.h>
#include <stdint.h>
#include <math.h>

typedef _Float16 half_t;
typedef _Float16 f16x8 __attribute__((ext_vector_type(8)));
typedef float f32x4 __attribute__((ext_vector_type(4)));

#define SLOPE 0.01f

__device__ inline float leaky(float v) { return v > 0.f ? v : SLOPE * v; }

__device__ inline void stage16(const half_t* g, half_t* l) {
    __builtin_amdgcn_global_load_lds(
        (const __attribute__((address_space(1))) unsigned int*)g,
        (__attribute__((address_space(3))) unsigned int*)l, 16, 0, 0);
}

__device__ inline float softplusf(float v) {
    return v > 20.f ? v : log1pf(expf(v));
}

// ---------------------------------------------------------------------------
// Border-zero for padded h1p (258x258x768 fp16): only the 1-px border needs
// zeros (interior is fully rewritten by conv1 before every conv2 read).
// 1028 border cells x 768 ch = 789,504 fp16 = 98,688 f16x8 writes.
// Replaces the 102 MB full memset (~20 us -> ~2 us).
// ---------------------------------------------------------------------------
__global__ void zb_kernel(half_t* __restrict__ h1p)
{
    unsigned v = blockIdx.x * 256u + threadIdx.x;      // vec8 index
    if (v >= 98688u) return;
    unsigned cell = v / 96u;                            // 768/8 = 96 vec8/cell
    unsigned off  = (v - cell * 96u) * 8u;
    unsigned y, x;
    if (cell < 258u)      { y = 0u;               x = cell; }
    else if (cell < 516u) { y = 257u;             x = cell - 258u; }
    else if (cell < 772u) { y = cell - 516u + 1u; x = 0u; }
    else                  { y = cell - 772u + 1u; x = 257u; }
    f16x8 z = {0, 0, 0, 0, 0, 0, 0, 0};
    *(f16x8*)(h1p + ((size_t)y * 258u + x) * 768u + off) = z;
}

// ---------------------------------------------------------------------------
// Weight prep: cast/reorder conv weights to oc-major fp16 ("B^T" GEMM operand)
// ---------------------------------------------------------------------------
__global__ void prep_kernel(const float* __restrict__ W1, const float* __restrict__ W2,
                            const float* __restrict__ W3,
                            half_t* __restrict__ B1w, half_t* __restrict__ B2w,
                            half_t* __restrict__ B3w)
{
    const unsigned idx = blockIdx.x * 256u + threadIdx.x;
    const unsigned n2 = 768u * 6912u;                 // 5,308,416
    if (idx < n2) {
        unsigned oc = idx / 6912u;
        unsigned rem = idx - oc * 6912u;
        unsigned tap = rem / 768u;
        unsigned ic = rem - tap * 768u;
        unsigned ky = tap / 3u, kx = tap - ky * 3u;
        B2w[idx] = (half_t)W2[(((size_t)oc * 768u + ic) * 3u + ky) * 3u + kx];
    } else if (idx < n2 + 147456u) {
        unsigned i = idx - n2;
        B1w[i] = (half_t)W1[i];                       // W1 flat is already (oc,ic)
    } else if (idx < n2 + 294912u) {
        unsigned i = idx - n2 - 147456u;
        B3w[i] = (half_t)W3[i];                       // W3 flat is already (oc,ic)
    }
}

// ---------------------------------------------------------------------------
// Per-window linear attention. One block per window. Writes feat NHWC fp16.
// ---------------------------------------------------------------------------
__global__ __launch_bounds__(256, 2)
void attn_kernel(const float* __restrict__ x,
                 const float* __restrict__ Wq, const float* __restrict__ bq,
                 const float* __restrict__ Wk, const float* __restrict__ bk,
                 const float* __restrict__ Wv, const float* __restrict__ bv,
                 const float* __restrict__ Wo, const float* __restrict__ bo,
                 half_t* __restrict__ featN)
{
    __shared__ half_t xls[192 * 65];
    __shared__ float wqL[512], wkL[512], wvL[512], woL[512];
    __shared__ float bqL[8], bkL[8], bvL[8], boL[64];
    __shared__ float kls[192 * 9], vls[192 * 9];
    __shared__ float sls[64];

    const int t = threadIdx.x;
    const int blk = blockIdx.x;
    const int b = blk >> 10;
    const int n = blk & 1023;
    const int wi = n >> 5, wj = n & 31;

    for (int i = t; i < 512; i += 256) {
        wqL[i] = Wq[i]; wkL[i] = Wk[i]; wvL[i] = Wv[i]; woL[i] = Wo[i];
    }
    if (t < 8)  { bqL[t] = bq[t]; bkL[t] = bk[t]; bvL[t] = bv[t]; }
    if (t < 64) boL[t] = bo[t];

    #pragma unroll
    for (int i = 0; i < 6; ++i) {
        int idx = t + i * 256;                 // 0..1535 = (c,py)
        int c = idx >> 3, py = idx & 7;
        const float* src = x + (((size_t)b * 192 + c) * 256 + (wi * 8 + py)) * 256 + wj * 8;
        float4 v0 = *(const float4*)src;
        float4 v1 = *(const float4*)(src + 4);
        half_t* dst = &xls[c * 65 + py * 8];
        dst[0] = (half_t)v0.x; dst[1] = (half_t)v0.y; dst[2] = (half_t)v0.z; dst[3] = (half_t)v0.w;
        dst[4] = (half_t)v1.x; dst[5] = (half_t)v1.y; dst[6] = (half_t)v1.z; dst[7] = (half_t)v1.w;
    }
    __syncthreads();

    float qf[8], kf[8], vf[8];
    if (t < 192) {
        #pragma unroll
        for (int d = 0; d < 8; ++d) { qf[d] = bqL[d]; kf[d] = bkL[d]; vf[d] = bvL[d]; }
        const half_t* xr = &xls[t * 65];
        for (int p = 0; p < 64; ++p) {
            float xv = (float)xr[p];
            const float* wqp = &wqL[p * 8];
            const float* wkp = &wkL[p * 8];
            const float* wvp = &wvL[p * 8];
            #pragma unroll
            for (int d = 0; d < 8; ++d) {
                qf[d] += xv * wqp[d];
                kf[d] += xv * wkp[d];
                vf[d] += xv * wvp[d];
            }
        }
        #pragma unroll
        for (int d = 0; d < 8; ++d) {
            qf[d] = softplusf(qf[d]);
            kf[d] = softplusf(kf[d]);
            kls[t * 9 + d] = kf[d];
            vls[t * 9 + d] = vf[d];
        }
    }
    __syncthreads();
    if (t < 64) {
        int e = t >> 3, dd = t & 7;
        float s = 0.f;
        for (int c = 0; c < 192; ++c) s += kls[c * 9 + e] * vls[c * 9 + dd];
        sls[t] = s;
    }
    __syncthreads();
    if (t < 192) {
        float rf[8];
        #pragma unroll
        for (int d = 0; d < 8; ++d) {
            float s = 0.f;
            #pragma unroll
            for (int e = 0; e < 8; ++e) s += qf[e] * sls[e * 8 + d];
            rf[d] = s;
        }
        half_t* xr = &xls[t * 65];
        for (int p = 0; p < 64; ++p) {
            float a = boL[p];
            #pragma unroll
            for (int d = 0; d < 8; ++d) a += rf[d] * woL[d * 64 + p];
            xr[p] = (half_t)((float)xr[p] + a);
        }
    }
    __syncthreads();
    half_t* dst = featN + ((size_t)b * 65536 + (size_t)n * 64) * 192;
    for (int i = 0; i < 48; ++i) {
        int idx = t + i * 256;                 // 0..12287 = p*192 + c
        int p = idx / 192, c = idx - p * 192;
        dst[idx] = xls[c * 65 + p];
    }
}

// ---------------------------------------------------------------------------
// conv1: 1x1 192->768 + leaky. GEMM M=65536 (one batch), N=768, K=192.
// ---------------------------------------------------------------------------
__global__ __launch_bounds__(256, 2)
void conv1_kernel(const half_t* __restrict__ featN, const half_t* __restrict__ B1w,
                  const float* __restrict__ b1, half_t* __restrict__ h1p, int batch)
{
    __shared__ half_t As[128 * 64];
    __shared__ half_t Bs[128 * 64];
    const int t = threadIdx.x;
    const int lane = t & 63;
    const int w = t >> 6;
    const int m0 = blockIdx.x * 128;
    const int n0 = blockIdx.y * 128;
    const int wm = (w >> 1) * 64, wn = (w & 1) * 64;
    const int rbase = t >> 3;
    const int g = (t & 7) ^ (rbase & 7);
    const int ar = lane & 15, kc = lane >> 4;

    f32x4 acc[4][4];
    #pragma unroll
    for (int i = 0; i < 4; ++i)
        #pragma unroll
        for (int j = 0; j < 4; ++j) acc[i][j] = (f32x4){0.f, 0.f, 0.f, 0.f};

    const size_t mb = (size_t)batch * 65536 + m0;

    for (int s = 0; s < 3; ++s) {
        const int k0 = s * 64;
        const half_t* ga = featN + (mb + rbase) * 192 + k0 + g * 8;
        const half_t* gb = B1w + (size_t)(n0 + rbase) * 192 + k0 + g * 8;
        half_t* la = As + t * 8;
        half_t* lb = Bs + t * 8;
        #pragma unroll
        for (int i = 0; i < 4; ++i) {
            stage16(ga + (size_t)32 * i * 192, la + 2048 * i);
            stage16(gb + (size_t)32 * i * 192, lb + 2048 * i);
        }
        __syncthreads();
        #pragma unroll
        for (int kh = 0; kh < 2; ++kh) {
            f16x8 af[4], bfr[4];
            const int c = kh * 4 + kc;
            #pragma unroll
            for (int mf = 0; mf < 4; ++mf) {
                int r = wm + mf * 16 + ar;
                af[mf] = *(const f16x8*)&As[(r * 8 + (c ^ (r & 7))) * 8];
            }
            #pragma unroll
            for (int nf = 0; nf < 4; ++nf) {
                int r = wn + nf * 16 + ar;
                bfr[nf] = *(const f16x8*)&Bs[(r * 8 + (c ^ (r & 7))) * 8];
            }
            #pragma unroll
            for (int mf = 0; mf < 4; ++mf)
                #pragma unroll
                for (int nf = 0; nf < 4; ++nf)
                    acc[mf][nf] = __builtin_amdgcn_mfma_f32_16x16x32_f16(af[mf], bfr[nf], acc[mf][nf], 0, 0, 0);
        }
        __syncthreads();
    }

    const int y = m0 >> 8, x0 = m0 & 255;
    half_t* outrow = h1p + ((size_t)(y + 1) * 258 + (x0 + 1)) * 768;
    #pragma unroll
    for (int nf = 0; nf < 4; ++nf) {
        int n = n0 + wn + nf * 16 + ar;
        float bias = b1[n];
        #pragma unroll
        for (int mf = 0; mf < 4; ++mf) {
            #pragma unroll
            for (int r4 = 0; r4 < 4; ++r4) {
                int local = wm + mf * 16 + kc * 4 + r4;
                outrow[(size_t)local * 768 + n] = (half_t)leaky(acc[mf][nf][r4] + bias);
            }
        }
    }
}

// ---------------------------------------------------------------------------
// conv2 v11 = v10 (wall 2799us, conv2 ~640us/52.5%, FETCH ideal) with only
// semantics-free SB0s removed: the SB0 INSIDE the post-MFMA boundary-read
// groups (those 12 reads are consumed by LGKM(12)-waits-for-all, so internal
// order is irrelevant). All SB0s that define counted-wait ordering are kept
// (e.g. RDB-before-RDA feeding ph2/ph6's LGKM(8) oldest-4 semantics).
// ---------------------------------------------------------------------------
__device__ __forceinline__ void c2_stage_A(half_t* As, int buf, int h,
    const half_t* __restrict__ h1p, int y, int kstep, int t, int cg)
{
    const int icc = kstep / 9, tap = kstep - icc * 9;   // tap inner (v10)
    const int ky = tap / 3, kx = tap - ky * 3;
    const int row0 = t >> 3;
    const half_t* g = h1p + ((size_t)(y + ky) * 258 + (kx + h * 128 + row0)) * 768
                      + icc * 64 + cg;
    half_t* l = As + (buf * 2 + h) * 8192 + t * 8;
    stage16(g, l);
    stage16(g + (size_t)64 * 768, l + 4096);
}

__device__ __forceinline__ void c2_stage_B(half_t* Bs, int buf, int h,
    const half_t* __restrict__ B2w, int n0, int kstep, int t, int cg)
{
    const int icc = kstep / 9, tap = kstep - icc * 9;   // tap inner (v10)
    const int row0 = t >> 3;
    const half_t* g = B2w + (size_t)(n0 + h * 128 + row0) * 6912
                      + tap * 768 + icc * 64 + cg;
    half_t* l = Bs + (buf * 2 + h) * 8192 + t * 8;
    stage16(g, l);
    stage16(g + (size_t)64 * 6912, l + 4096);
}

#define SBAR __builtin_amdgcn_s_barrier()
#define SB0  __builtin_amdgcn_sched_barrier(0)
#define LGKM(N) asm volatile("s_waitcnt lgkmcnt(" #N ")" ::: "memory")
#define VMC(N)  asm volatile("s_waitcnt vmcnt(" #N ")" ::: "memory")

// 8 ds_read_b128 into af[MQ] (frags for both kh of quadrant row-half MQ)
#define RDA(MQ, BUF)                                                             \
  _Pragma("unroll")                                                              \
  for (int mf = 0; mf < 4; ++mf)                                                 \
    _Pragma("unroll")                                                            \
    for (int kh = 0; kh < 2; ++kh) {                                             \
      const int lr = wm * 64 + mf * 16 + ar;                                     \
      const int ch = (kh * 4 + kc) ^ (lr & 7);                                   \
      af[MQ][mf][kh] = *(const f16x8*)&As[((BUF)*2 + (MQ))*8192 + lr*64 + ch*8]; \
    }

// 4 ds_read_b128 into bf[NQ]
#define RDB(NQ, BUF)                                                             \
  _Pragma("unroll")                                                              \
  for (int nf = 0; nf < 2; ++nf)                                                 \
    _Pragma("unroll")                                                            \
    for (int kh = 0; kh < 2; ++kh) {                                             \
      const int lc = wn * 32 + nf * 16 + ar;                                     \
      const int ch = (kh * 4 + kc) ^ (lc & 7);                                   \
      bf[NQ][nf][kh] = *(const f16x8*)&Bs[((BUF)*2 + (NQ))*8192 + lc*64 + ch*8]; \
    }

#define MMA16(MQ, NQ)                                                            \
  {                                                                              \
    __builtin_amdgcn_s_setprio(1);                                               \
    _Pragma("unroll")                                                            \
    for (int kh = 0; kh < 2; ++kh)                                               \
      _Pragma("unroll")                                                          \
      for (int mf = 0; mf < 4; ++mf)                                             \
        _Pragma("unroll")                                                        \
        for (int nf = 0; nf < 2; ++nf)                                           \
          acc[(MQ)*2+(NQ)][mf][nf] = __builtin_amdgcn_mfma_f32_16x16x32_f16(     \
              af[MQ][mf][kh], bf[NQ][nf][kh], acc[(MQ)*2+(NQ)][mf][nf], 0, 0, 0);\
    __builtin_amdgcn_s_setprio(0);                                               \
  }

__global__ __launch_bounds__(512, 2)
void conv2_kernel(const half_t* __restrict__ h1p, const half_t* __restrict__ B2w,
                  const float* __restrict__ b2, half_t* __restrict__ h2)
{
    __shared__ half_t As[4 * 8192];    // [buf][half][128][64] f16 = 64 KiB
    __shared__ half_t Bs[4 * 8192];

    const int t = threadIdx.x;
    const int lane = t & 63;
    const int w = t >> 6;
    const int wm = w >> 2, wn = w & 3;            // 2x4 wave grid inside a quadrant
    const int ar = lane & 15, kc = lane >> 4;
    const int cg = (((t & 7) ^ ((t >> 3) & 7)) << 3);  // pre-swizzled source chunk

    // v4 grid: nt innermost + XCD-chunked mtile bands.
    const int bid = blockIdx.x;
    const int xcd = bid & 7, sid = bid >> 3;      // 96 blocks per XCD
    const int wg = xcd * 96 + sid;                // 768 = 8 XCD * 96
    const int mtile = wg / 3;
    const int nt = wg - mtile * 3;
    const int y = mtile;
    const int m0 = mtile * 256;
    const int n0 = nt * 256;

    f32x4 acc[4][4][2];
    #pragma unroll
    for (int q = 0; q < 4; ++q)
        #pragma unroll
        for (int i = 0; i < 4; ++i)
            #pragma unroll
            for (int j = 0; j < 2; ++j) acc[q][i][j] = (f32x4){0.f, 0.f, 0.f, 0.f};

    f16x8 af[2][4][2];   // [MQ][mf][kh]
    f16x8 bf[2][2][2];   // [NQ][nf][kh]

    // Prologue: stage buf0<-k0, buf1<-k1 fully; drain; issue boundary reads.
    c2_stage_A(As, 0, 0, h1p, y, 0, t, cg);
    c2_stage_A(As, 0, 1, h1p, y, 0, t, cg);
    c2_stage_B(Bs, 0, 0, B2w, n0, 0, t, cg);
    c2_stage_B(Bs, 0, 1, B2w, n0, 0, t, cg);
    c2_stage_A(As, 1, 0, h1p, y, 1, t, cg);
    c2_stage_A(As, 1, 1, h1p, y, 1, t, cg);
    c2_stage_B(Bs, 1, 0, B2w, n0, 1, t, cg);
    c2_stage_B(Bs, 1, 1, B2w, n0, 1, t, cg);
    VMC(0);
    SBAR; SB0;
    RDB(0, 0); SB0;
    RDA(0, 0);

    // Steady: 53 iterations (compute kt 0..105; stage up to kt 107).
    for (int i = 0; i < 53; ++i) {
        const int k2 = 2 * i + 2;
        const int k3 = 2 * i + 3;
        // ph1 (q00 buf0): read-ahead bf1,af1 of buf0.
        RDB(1, 0); SB0;                         // SB0 kept: ph2's LGKM(8) needs RDB oldest
        RDA(1, 0);
        LGKM(12); SB0;
        MMA16(0, 0);
        SBAR;                                   // protects ph2's h0 stage
        // ph2 (q01 buf0): stage A0h0,B0h0 <- k2.
        c2_stage_A(As, 0, 0, h1p, y, k2, t, cg);
        c2_stage_B(Bs, 0, 0, B2w, n0, k2, t, cg);
        LGKM(8); SB0;
        MMA16(0, 1);
        // (barrier removed: ph3 has no LDS writes/reads to order)
        // ph3 (q11 buf0).
        LGKM(0); SB0;
        MMA16(1, 1);
        SBAR;                                   // protects ph4's h1 stage
        // ph4 (q10 buf0): stage A0h1,B0h1 <- k2; vmcnt(8); post-reads buf1.
        c2_stage_A(As, 0, 1, h1p, y, k2, t, cg);
        c2_stage_B(Bs, 0, 1, B2w, n0, k2, t, cg);
        VMC(8);
        SBAR; SB0;                              // all waves drained -> buf1 ready
        MMA16(1, 0);
        SB0;                                    // SB0 kept: pin reads after MFMA (v5 guard)
        RDB(0, 1);
        RDA(0, 1);                              // (internal SB0 removed: LGKM(12) waits all)
        // (trailing barrier removed)
        // ph5 (q00 buf1): read-ahead bf1,af1 of buf1.
        RDB(1, 1); SB0;
        RDA(1, 1);
        LGKM(12); SB0;
        MMA16(0, 0);
        SBAR;                                   // protects ph6's h0 stage
        // ph6 (q01 buf1): stage A1h0,B1h0 <- k3.
        c2_stage_A(As, 1, 0, h1p, y, k3, t, cg);
        c2_stage_B(Bs, 1, 0, B2w, n0, k3, t, cg);
        LGKM(8); SB0;
        MMA16(0, 1);
        // (barrier removed)
        // ph7 (q11 buf1).
        LGKM(0); SB0;
        MMA16(1, 1);
        SBAR;                                   // protects ph8's h1 stage
        // ph8 (q10 buf1): stage A1h1,B1h1 <- k3; vmcnt(8); post-reads buf0 next.
        c2_stage_A(As, 1, 1, h1p, y, k3, t, cg);
        c2_stage_B(Bs, 1, 1, B2w, n0, k3, t, cg);
        VMC(8);
        SBAR; SB0;                              // all waves drained -> buf0 ready
        MMA16(1, 0);
        SB0;                                    // SB0 kept (v5 guard)
        RDB(0, 0);
        RDA(0, 0);                              // (internal SB0 removed)
        // (trailing barrier removed)
    }
    // Tail (kt 106,107): no stages, no next-buffer reads.
    {
        // ph1
        RDB(1, 0); SB0;
        RDA(1, 0);
        LGKM(12); SB0;
        MMA16(0, 0);
        SBAR;
        // ph2
        LGKM(8); SB0;
        MMA16(0, 1);
        // (barrier removed)
        // ph3
        LGKM(0); SB0;
        MMA16(1, 1);
        SBAR;
        // ph4: drain all remaining stages (prev ph6/ph8), then buf1 reads.
        VMC(0);
        SBAR; SB0;
        MMA16(1, 0);
        SB0;
        RDB(0, 1);
        RDA(0, 1);
        // (trailing barrier removed)
        // ph5
        RDB(1, 1); SB0;
        RDA(1, 1);
        LGKM(12); SB0;
        MMA16(0, 0);
        SBAR;
        // ph6
        LGKM(8); SB0;
        MMA16(0, 1);
        // (barrier removed)
        // ph7
        LGKM(0); SB0;
        MMA16(1, 1);
        SBAR;
        // ph8
        MMA16(1, 0);
    }

    // Epilogue: bias + leaky, write NHWC fp16.
    #pragma unroll
    for (int q = 0; q < 4; ++q) {
        const int mq = q >> 1, nq = q & 1;
        #pragma unroll
        for (int nf = 0; nf < 2; ++nf) {
            const int col = n0 + nq * 128 + wn * 32 + nf * 16 + ar;
            const float bias = b2[col];
            #pragma unroll
            for (int mf = 0; mf < 4; ++mf) {
                const int row = m0 + mq * 128 + wm * 64 + mf * 16 + kc * 4;
                half_t* op = h2 + (size_t)row * 768 + col;
                #pragma unroll
                for (int r4 = 0; r4 < 4; ++r4)
                    op[(size_t)r4 * 768] = (half_t)leaky(acc[q][mf][nf][r4] + bias);
            }
        }
    }
}

// ---------------------------------------------------------------------------
// conv3: 1x1 768->192 + leaky. GEMM M=65536 (one batch), N=192, K=768.
// ---------------------------------------------------------------------------
__global__ __launch_bounds__(256, 2)
void conv3_kernel(const half_t* __restrict__ h2, const half_t* __restrict__ B3w,
                  const float* __restrict__ b3, float* __restrict__ out, int batch)
{
    __shared__ half_t As[128 * 64];
    __shared__ half_t Bs[192 * 64];
    const int t = threadIdx.x;
    const int lane = t & 63;
    const int w = t >> 6;
    const int m0 = blockIdx.x * 128;
    const int wm = (w >> 1) * 64;
    const int wn = (w & 1) * 96;
    const int rbase = t >> 3;
    const int g = (t & 7) ^ (rbase & 7);
    const int ar = lane & 15, kc = lane >> 4;

    f32x4 acc[4][6];
    #pragma unroll
    for (int i = 0; i < 4; ++i)
        #pragma unroll
        for (int j = 0; j < 6; ++j) acc[i][j] = (f32x4){0.f, 0.f, 0.f, 0.f};

    for (int s = 0; s < 12; ++s) {
        const int k0 = s * 64;
        const half_t* ga = h2 + (size_t)(m0 + rbase) * 768 + k0 + g * 8;
        const half_t* gb = B3w + (size_t)rbase * 768 + k0 + g * 8;
        half_t* la = As + t * 8;
        half_t* lb = Bs + t * 8;
        #pragma unroll
        for (int i = 0; i < 4; ++i) stage16(ga + (size_t)32 * i * 768, la + 2048 * i);
        #pragma unroll
        for (int i = 0; i < 6; ++i) stage16(gb + (size_t)32 * i * 768, lb + 2048 * i);
        __syncthreads();
        #pragma unroll
        for (int kh = 0; kh < 2; ++kh) {
            f16x8 af[4], bfr[6];
            const int c = kh * 4 + kc;
            #pragma unroll
            for (int mf = 0; mf < 4; ++mf) {
                int r = wm + mf * 16 + ar;
                af[mf] = *(const f16x8*)&As[(r * 8 + (c ^ (r & 7))) * 8];
            }
            #pragma unroll
            for (int nf = 0; nf < 6; ++nf) {
                int r = wn + nf * 16 + ar;
                bfr[nf] = *(const f16x8*)&Bs[(r * 8 + (c ^ (r & 7))) * 8];
            }
            #pragma unroll
            for (int mf = 0; mf < 4; ++mf)
                #pragma unroll
                for (int nf = 0; nf < 6; ++nf)
                    acc[mf][nf] = __builtin_amdgcn_mfma_f32_16x16x32_f16(af[mf], bfr[nf], acc[mf][nf], 0, 0, 0);
        }
        __syncthreads();
    }

    #pragma unroll
    for (int nf = 0; nf < 6; ++nf) {
        int n = wn + nf * 16 + ar;
        float bias = b3[n];
        float* op = out + ((size_t)batch * 192 + n) * 65536 + m0;
        #pragma unroll
        for (int mf = 0; mf < 4; ++mf) {
            int local = wm + mf * 16 + kc * 4;
            f32x4 v;
            #pragma unroll
            for (int r4 = 0; r4 < 4; ++r4) v[r4] = leaky(acc[mf][nf][r4] + bias);
            *(f32x4*)(op + local) = v;
        }
    }
}

// ---------------------------------------------------------------------------
extern "C" void kernel_launch(void* const* d_in, const int* in_sizes, int n_in,
                              void* d_out, int out_size, void* d_ws, size_t ws_size,
                              hipStream_t stream)
{
    const float* x  = (const float*)d_in[0];
    const float* Wq = (const float*)d_in[1];
    const float* bq = (const float*)d_in[2];
    const float* Wk = (const float*)d_in[3];
    const float* bk = (const float*)d_in[4];
    const float* Wv = (const float*)d_in[5];
    const float* bv = (const float*)d_in[6];
    const float* Wo = (const float*)d_in[7];
    const float* bo = (const float*)d_in[8];
    const float* W1 = (const float*)d_in[9];
    const float* b1 = (const float*)d_in[10];
    const float* W2 = (const float*)d_in[11];
    const float* b2 = (const float*)d_in[12];
    const float* W3 = (const float*)d_in[13];
    const float* b3 = (const float*)d_in[14];

    char* ws = (char*)d_ws;
    const size_t OFF_B1   = 0;
    const size_t OFF_B3   = 294912;
    const size_t OFF_B2   = 589824;
    const size_t OFF_FEAT = 11206656;
    const size_t OFF_H1P  = 111869952;
    const size_t OFF_H2   = 214124544;
    const size_t WS_NEED  = 314787840;
    if (ws_size < WS_NEED) return;

    half_t* B1w   = (half_t*)(ws + OFF_B1);
    half_t* B3w   = (half_t*)(ws + OFF_B3);
    half_t* B2w   = (half_t*)(ws + OFF_B2);
    half_t* featN = (half_t*)(ws + OFF_FEAT);
    half_t* h1p   = (half_t*)(ws + OFF_H1P);
    half_t* h2    = (half_t*)(ws + OFF_H2);

    // zero only the 1-px border of h1p (interior fully rewritten by conv1
    // before every conv2 read; border never written after this).
    zb_kernel<<<386, 256, 0, stream>>>(h1p);
    prep_kernel<<<21888, 256, 0, stream>>>(W1, W2, W3, B1w, B2w, B3w);
    attn_kernel<<<4096, 256, 0, stream>>>(x, Wq, bq, Wk, bk, Wv, bv, Wo, bo, featN);

    for (int b = 0; b < 4; ++b) {
        conv1_kernel<<<dim3(512, 6), 256, 0, stream>>>(featN, B1w, b1, h1p, b);
        conv2_kernel<<<768, 512, 0, stream>>>(h1p, B2w, b2, h2);
        conv3_kernel<<<dim3(512, 1), 256, 0, stream>>>(h2, B3w, b3, (float*)d_out, b);
    }
}